// Round 4
// baseline (247.733 us; speedup 1.0000x reference)
//
#include <hip/hip_runtime.h>
#include <stdint.h>

// ---------------------------------------------------------------------------
// CausalSelfAttention (T=4096, DIM=1024, 16 heads x 64) on gfx950, bf16 MFMA.
// Pipeline: cast->bf16 | rope tables | GEMM1 qkv | fuse(vmix,rms,rope) |
//           transpose V | flash attention (swapped 32x32, 2-wave blocks,
//           ones-MFMA rowsum, defer-max) | GEMM2 -> fp32 out
// ---------------------------------------------------------------------------

typedef __attribute__((ext_vector_type(8))) __bf16 bf16x8;
typedef __attribute__((ext_vector_type(8))) unsigned short u16x8;
typedef __attribute__((ext_vector_type(4))) float f32x4;
typedef __attribute__((ext_vector_type(16))) float f32x16;

union U8 { u16x8 s; bf16x8 b; };
union PF { unsigned int u[4]; u16x8 s; bf16x8 b; };

__device__ __forceinline__ float bf2f(unsigned short u) {
  union { unsigned int i; float f; } c; c.i = ((unsigned int)u) << 16; return c.f;
}
__device__ __forceinline__ unsigned short f2bf(float f) {
  union { __bf16 h; unsigned short u; } c; c.h = (__bf16)f; return c.u;
}
__device__ __forceinline__ unsigned int pk2(float lo, float hi) {
  return (unsigned int)f2bf(lo) | ((unsigned int)f2bf(hi) << 16);
}

// async global->LDS, 16B per lane; LDS dest is wave-uniform base + lane*16
#define GLOAD16(gp, lp)                                                         \
  __builtin_amdgcn_global_load_lds(                                             \
      (const __attribute__((address_space(1))) void*)(gp),                      \
      (__attribute__((address_space(3))) void*)(lp), 16, 0, 0)

#define MFMA16(a, b, c) __builtin_amdgcn_mfma_f32_16x16x32_bf16((a), (b), (c), 0, 0, 0)
#define MFMA32(a, b, c) __builtin_amdgcn_mfma_f32_32x32x16_bf16((a), (b), (c), 0, 0, 0)

constexpr float ATTN_SCALE = 0.12f;
constexpr float LOG2E = 1.44269504088896340736f;
constexpr float QSCALE = ATTN_SCALE * LOG2E;  // folded into Q at fuse stage

// --------------------------- rope tables -----------------------------------
__global__ void rope_tab(float* __restrict__ ct, float* __restrict__ st) {
  const int i = blockIdx.x * 256 + threadIdx.x;
  if (i >= 4096 * 32) return;
  const int tt = i >> 5, k = i & 31;
  float cv = 1.0f, sv = 0.0f;
  if (k < 16) {
    const float af = powf(1.0f / 1024.0f, (float)k * (1.0f / 15.0f));
    const float th = (float)tt * af;
    cv = cosf(th);
    sv = sinf(th);
  }
  ct[i] = cv; st[i] = sv;
}

// --------------------------- f32 -> bf16 cast ------------------------------
__global__ void cast_f2b8(const float* __restrict__ in, unsigned short* __restrict__ out, int n8) {
  const int i = blockIdx.x * 256 + threadIdx.x;
  if (i >= n8) return;
  const float4 a = ((const float4*)in)[2 * i];
  const float4 b = ((const float4*)in)[2 * i + 1];
  u16x8 o;
  o[0] = f2bf(a.x); o[1] = f2bf(a.y); o[2] = f2bf(a.z); o[3] = f2bf(a.w);
  o[4] = f2bf(b.x); o[5] = f2bf(b.y); o[6] = f2bf(b.z); o[7] = f2bf(b.w);
  ((u16x8*)out)[i] = o;
}

// --------------------------- GEMM: C[M][N] = A[M][K] * B[N][K]^T -----------
template <int OUT_BF16>
__global__ __launch_bounds__(256) void gemm_bt(
    const unsigned short* __restrict__ A, const unsigned short* __restrict__ B,
    void* __restrict__ Cout, int M, int N, int K) {
  __shared__ unsigned short lA[128 * 32];
  __shared__ unsigned short lB[128 * 32];
  const int nbn = N >> 7;
  const int bm = blockIdx.x / nbn, bn = blockIdx.x % nbn;
  const int t = threadIdx.x;
  const int w = t >> 6, l = t & 63;
  const int g = l >> 4, c = l & 15;
  const int wr = (w >> 1) * 64, wc = (w & 1) * 64;

  const int srow = t >> 2;
  const int scol = ((t & 3) << 4) ^ ((srow & 3) << 4);  // byte col, XOR swizzle
  const char* ga = (const char*)(A + (size_t)(bm * 128 + srow) * K) + scol;
  const char* gb = (const char*)(B + (size_t)(bn * 128 + srow) * K) + scol;
  const size_t rowK2 = (size_t)64 * K * 2;
  char* la_dst = (char*)lA + t * 16;
  char* lb_dst = (char*)lB + t * 16;

  f32x4 acc[4][4] = {};

  for (int kt = 0; kt < K; kt += 32) {
    const char* gak = ga + (size_t)kt * 2;
    const char* gbk = gb + (size_t)kt * 2;
    GLOAD16(gak, la_dst);
    GLOAD16(gak + rowK2, la_dst + 4096);
    GLOAD16(gbk, lb_dst);
    GLOAD16(gbk + rowK2, lb_dst + 4096);
    __syncthreads();
    U8 af[4], bfr[4];
#pragma unroll
    for (int mi = 0; mi < 4; ++mi) {
      const int row = wr + 16 * mi + c;
      af[mi].s = *(const u16x8*)((const char*)lA + row * 64 + ((16 * g) ^ ((row & 3) << 4)));
    }
#pragma unroll
    for (int ni = 0; ni < 4; ++ni) {
      const int row = wc + 16 * ni + c;
      bfr[ni].s = *(const u16x8*)((const char*)lB + row * 64 + ((16 * g) ^ ((row & 3) << 4)));
    }
#pragma unroll
    for (int mi = 0; mi < 4; ++mi)
#pragma unroll
      for (int ni = 0; ni < 4; ++ni)
        acc[mi][ni] = MFMA16(af[mi].b, bfr[ni].b, acc[mi][ni]);
    __syncthreads();
  }
#pragma unroll
  for (int mi = 0; mi < 4; ++mi) {
#pragma unroll
    for (int ni = 0; ni < 4; ++ni) {
#pragma unroll
      for (int r = 0; r < 4; ++r) {
        const int row = bm * 128 + wr + 16 * mi + 4 * g + r;
        const int col = bn * 128 + wc + 16 * ni + c;
        const float v = acc[mi][ni][r];
        if (OUT_BF16)
          ((unsigned short*)Cout)[(size_t)row * N + col] = f2bf(v);
        else
          ((float*)Cout)[(size_t)row * N + col] = v;
      }
    }
  }
}

// --------------------------- fuse: vmix + rmsnorm + rope -------------------
__device__ __forceinline__ void load64f(const unsigned short* p, float* x) {
#pragma unroll
  for (int j = 0; j < 8; ++j) {
    const u16x8 v = *(const u16x8*)(p + 8 * j);
#pragma unroll
    for (int e = 0; e < 8; ++e) x[8 * j + e] = bf2f(v[e]);
  }
}

__device__ __forceinline__ void rmsrope_store(const float* x, const float* ct, const float* st,
                                              unsigned short* outp, float pscale) {
  float ms = 0.f;
#pragma unroll
  for (int j = 0; j < 64; ++j) ms += x[j] * x[j];
  const float sc = rsqrtf(ms * (1.0f / 64.0f) + 1.1920928955078125e-7f) * pscale;
  float y[64];
#pragma unroll
  for (int j = 0; j < 32; ++j) {
    const float cc = ct[j], ss = st[j];
    const float a = x[j] * sc, b = x[j + 32] * sc;
    y[j] = a * cc + b * ss;
    y[j + 32] = b * cc - a * ss;
  }
#pragma unroll
  for (int j = 0; j < 8; ++j) {
    u16x8 o;
#pragma unroll
    for (int e = 0; e < 8; ++e) o[e] = f2bf(y[8 * j + e]);
    *(u16x8*)(outp + 8 * j) = o;
  }
}

__global__ __launch_bounds__(256) void fuse_qkv(
    const unsigned short* __restrict__ qkv,  // [4096][3072] bf16
    const float* __restrict__ ve,            // [4096][1024]
    const float* __restrict__ lam,           // [2]
    const float* __restrict__ ct, const float* __restrict__ st,  // [4096][32]
    unsigned short* __restrict__ Qo,  // [16][4096][64]  (pre-scaled by QSCALE)
    unsigned short* __restrict__ Ko,  // [16][4096][64]
    unsigned short* __restrict__ Vo)  // [16][4096][64]
{
  const int gid = blockIdx.x * 256 + threadIdx.x;  // 65536 = 4096 t * 16 h
  const int tt = gid >> 4, h = gid & 15;
  const unsigned short* base = qkv + (size_t)tt * 3072 + h * 64;
  const float* ctp = ct + tt * 32;
  const float* stp = st + tt * 32;
  float x[64];
  load64f(base, x);
  rmsrope_store(x, ctp, stp, Qo + ((size_t)h * 4096 + tt) * 64, QSCALE);
  load64f(base + 1024, x);
  rmsrope_store(x, ctp, stp, Ko + ((size_t)h * 4096 + tt) * 64, 1.0f);
  const float l0 = lam[0], l1 = lam[1];
  const float* vp = ve + (size_t)tt * 1024 + h * 64;
  load64f(base + 2048, x);
  unsigned short* vo = Vo + ((size_t)h * 4096 + tt) * 64;
#pragma unroll
  for (int j = 0; j < 8; ++j) {
    u16x8 o;
#pragma unroll
    for (int e = 0; e < 8; ++e) o[e] = f2bf(l0 * x[8 * j + e] + l1 * vp[8 * j + e]);
    *(u16x8*)(vo + 8 * j) = o;
  }
}

// --------------------------- V transpose: [16][4096][64] -> [16][64][4096] -
__global__ __launch_bounds__(256) void transpose_v(const unsigned short* __restrict__ vin,
                                                   unsigned short* __restrict__ vout) {
  __shared__ unsigned short tile[64][72];
  const int h = (int)(blockIdx.x & 15), tb = (int)(blockIdx.x >> 4);
  const int t = threadIdx.x;
  const int r = t >> 2, c0 = (t & 3) * 16;
  const unsigned short* src = vin + ((size_t)h * 4096 + tb * 64 + r) * 64 + c0;
#pragma unroll
  for (int j = 0; j < 16; ++j) tile[c0 + j][r] = src[j];
  __syncthreads();
  unsigned short* dst = vout + ((size_t)h * 64 + r) * 4096 + tb * 64 + c0;
#pragma unroll
  for (int j = 0; j < 16; ++j) dst[j] = tile[r][c0 + j];
}

// --------------------------- flash attention (swapped 32x32) ---------------
// block = (head, 64-row q block), 2 waves x 32 q rows. Grid 1024, j descending
// (longest first) -> fine-grained packing kills the tail that capped round 3.
// Swapped QK^T: S^T = mfma_32x32x16(K, Q); lane holds 32 kv values of ONE q
// row. Row-sum via ones-MFMA (osum accumulator; ls = osum[0], no shfl).
// Defer-max: skip alpha-rescale while __all(pm <= m+8) (P bounded by 2^8).
__global__ __launch_bounds__(128) void attn_fa(
    const unsigned short* __restrict__ Q,   // [16][4096][64] (scaled)
    const unsigned short* __restrict__ Kv,  // [16][4096][64]
    const unsigned short* __restrict__ VT,  // [16][64][4096]
    unsigned short* __restrict__ Y)         // [4096][1024]
{
  __shared__ unsigned short lk[2][64 * 64];   // K tile,  swizzled rows (128B)
  __shared__ unsigned short lv[2][64 * 64];   // V^T tile, swizzled rows

  const int h = (int)(blockIdx.x & 15);
  const int j = 63 - (int)(blockIdx.x >> 4);  // 0..63, longest first
  const int t = threadIdx.x;                  // 0..127 (2 waves)
  const int w = t >> 6, l = t & 63;
  const int lq = l & 31;    // this lane's q row (within wave tile)
  const int hi = l >> 5;    // kv half selector
  const int q0w = j * 64 + 32 * w;
  const int swz = (lq & 7) << 4;

  // Q fragments (B operand): lane holds Q[q0w+lq][16*dd + 8*hi .. +8]
  U8 qf[4];
  {
    const unsigned short* qp = Q + ((size_t)h * 4096 + q0w + lq) * 64 + 8 * hi;
#pragma unroll
    for (int dd = 0; dd < 4; ++dd) qf[dd].s = *(const u16x8*)(qp + 16 * dd);
  }

  U8 onesf;
#pragma unroll
  for (int e = 0; e < 8; ++e) onesf.s[e] = 0x3F80;  // bf16 1.0

  f32x16 o0 = {}, o1 = {};   // O^T accum: d rows 0-31 / 32-63, col q = lq
  f32x16 osum = {};          // row-sum accum (all D rows identical; use [0])
  float m = -3e38f;

  const int srow = t >> 3;                             // 0..15
  const int csw = ((t & 7) << 4) ^ ((srow & 7) << 4);  // pre-swizzled src col
  const unsigned short* kbase = Kv + (size_t)h * 4096 * 64;
  const unsigned short* vbase = VT + (size_t)h * 64 * 4096;

#define STAGE(buf, kv0)                                                          \
  do {                                                                           \
    char* lkd = (char*)lk[buf] + t * 16;                                         \
    char* lvd = (char*)lv[buf] + t * 16;                                         \
    _Pragma("unroll")                                                            \
    for (int cc = 0; cc < 4; ++cc) {                                             \
      GLOAD16((const char*)(kbase + (size_t)((kv0) + srow + 16 * cc) * 64) + csw,\
              lkd + 2048 * cc);                                                  \
      GLOAD16((const char*)(vbase + (size_t)(srow + 16 * cc) * 4096 + (kv0)) +   \
              csw, lvd + 2048 * cc);                                             \
    }                                                                            \
  } while (0)

  const int ntiles = j + 1;
  STAGE(0, 0);
  __syncthreads();
  int cur = 0;

  for (int ti = 0; ti < ntiles; ++ti) {
    const int kv0 = ti * 64;
    if (ti + 1 < ntiles) STAGE(cur ^ 1, kv0 + 64);

    const char* lkc = (const char*)lk[cur];
    const char* lvc = (const char*)lv[cur];
    const bool live1 = (kv0 + 32) <= (q0w + 31);  // sub-tile st=1 live?

    // ---- S^T = K * Q^T : two 32x32 tiles over kv ----
    __builtin_amdgcn_s_setprio(1);
    f32x16 s0 = {}, s1;
#pragma unroll
    for (int dd = 0; dd < 4; ++dd) {
      U8 kf;
      kf.s = *(const u16x8*)(lkc + lq * 128 + ((32 * dd + 16 * hi) ^ swz));
      s0 = MFMA32(kf.b, qf[dd].b, s0);
    }
    if (live1) {
      f32x16 z = {};
#pragma unroll
      for (int dd = 0; dd < 4; ++dd) {
        U8 kf;
        kf.s = *(const u16x8*)(lkc + 4096 + lq * 128 + ((32 * dd + 16 * hi) ^ swz));
        z = MFMA32(kf.b, qf[dd].b, z);
      }
      s1 = z;
    } else {
#pragma unroll
      for (int e = 0; e < 16; ++e) s1[e] = -3e38f;
    }
    __builtin_amdgcn_s_setprio(0);

    // ---- causal mask (element kv = kv0 + 32*st + (e&3)+8*(e>>2)+4*hi) ----
    const int thr0 = q0w + lq - kv0 - 4 * hi;  // mask if kvr_base > thr
    if (kv0 + 31 > q0w) {
#pragma unroll
      for (int e = 0; e < 16; ++e) {
        const int kvr = (e & 3) + 8 * (e >> 2);
        if (kvr > thr0) s0[e] = -3e38f;
      }
    }
    if (live1 && kv0 + 63 > q0w) {
      const int thr1 = thr0 - 32;
#pragma unroll
      for (int e = 0; e < 16; ++e) {
        const int kvr = (e & 3) + 8 * (e >> 2);
        if (kvr > thr1) s1[e] = -3e38f;
      }
    }

    // ---- online softmax: all values belong to q = lq ----
    float pm;
    {  // pairwise tree (encourage v_max3 + ILP, avoid 31-op serial chain)
      float t0 = fmaxf(s0[0], s0[1]), t1 = fmaxf(s0[2], s0[3]);
      float t2 = fmaxf(s0[4], s0[5]), t3 = fmaxf(s0[6], s0[7]);
      float t4 = fmaxf(s0[8], s0[9]), t5 = fmaxf(s0[10], s0[11]);
      float t6 = fmaxf(s0[12], s0[13]), t7 = fmaxf(s0[14], s0[15]);
      float u0 = fmaxf(fmaxf(t0, t1), fmaxf(t2, t3));
      float u1 = fmaxf(fmaxf(t4, t5), fmaxf(t6, t7));
      pm = fmaxf(u0, u1);
      if (live1) {
        float v0 = fmaxf(s1[0], s1[1]), v1 = fmaxf(s1[2], s1[3]);
        float v2 = fmaxf(s1[4], s1[5]), v3 = fmaxf(s1[6], s1[7]);
        float v4 = fmaxf(s1[8], s1[9]), v5 = fmaxf(s1[10], s1[11]);
        float v6 = fmaxf(s1[12], s1[13]), v7 = fmaxf(s1[14], s1[15]);
        float x0 = fmaxf(fmaxf(v0, v1), fmaxf(v2, v3));
        float x1 = fmaxf(fmaxf(v4, v5), fmaxf(v6, v7));
        pm = fmaxf(pm, fmaxf(x0, x1));
      }
    }
    pm = fmaxf(pm, __shfl_xor(pm, 32));
    if (!__all(pm <= m + 8.0f)) {  // defer-max: rescale only on real growth
      const float mn = fmaxf(m, pm);
      const float alpha = exp2f(m - mn);
#pragma unroll
      for (int e = 0; e < 16; ++e) { o0[e] *= alpha; o1[e] *= alpha; }
      osum[0] *= alpha;
      m = mn;
    }
#pragma unroll
    for (int e = 0; e < 16; ++e) s0[e] = exp2f(s0[e] - m);
    if (live1) {
#pragma unroll
      for (int e = 0; e < 16; ++e) s1[e] = exp2f(s1[e] - m);
    }

    // ---- P^T pack + redistribute + PV (O^T += V^T * P^T; osum += 1 * P^T) --
#define DO_SLAB(SV, B, KS)                                                       \
  do {                                                                           \
    const unsigned int ua = pk2(SV[8 * (B) + 0], SV[8 * (B) + 1]);               \
    const unsigned int ub = pk2(SV[8 * (B) + 2], SV[8 * (B) + 3]);               \
    const unsigned int uc = pk2(SV[8 * (B) + 4], SV[8 * (B) + 5]);               \
    const unsigned int ud = pk2(SV[8 * (B) + 6], SV[8 * (B) + 7]);               \
    const unsigned int sa = (unsigned int)__shfl_xor((int)ua, 32);               \
    const unsigned int sb = (unsigned int)__shfl_xor((int)ub, 32);               \
    const unsigned int sc = (unsigned int)__shfl_xor((int)uc, 32);               \
    const unsigned int sd = (unsigned int)__shfl_xor((int)ud, 32);               \
    PF pf;                                                                       \
    pf.u[0] = hi ? sc : ua;                                                      \
    pf.u[1] = hi ? sd : ub;                                                      \
    pf.u[2] = hi ? uc : sa;                                                      \
    pf.u[3] = hi ? ud : sb;                                                      \
    U8 vf0, vf1;                                                                 \
    const int vb = (32 * (KS) + 16 * hi) ^ swz;                                  \
    vf0.s = *(const u16x8*)(lvc + lq * 128 + vb);                                \
    vf1.s = *(const u16x8*)(lvc + 4096 + lq * 128 + vb);                         \
    __builtin_amdgcn_s_setprio(1);                                               \
    o0 = MFMA32(vf0.b, pf.b, o0);                                                \
    o1 = MFMA32(vf1.b, pf.b, o1);                                                \
    osum = MFMA32(onesf.b, pf.b, osum);                                          \
    __builtin_amdgcn_s_setprio(0);                                               \
  } while (0)

    DO_SLAB(s0, 0, 0);
    DO_SLAB(s0, 1, 1);
    if (live1) {
      DO_SLAB(s1, 0, 2);
      DO_SLAB(s1, 1, 3);
    }
#undef DO_SLAB
    __syncthreads();
    cur ^= 1;
  }
#undef STAGE

  // ---- epilogue: y = O^T / ls; transpose via per-wave LDS; coalesced store
  const float inv = 1.0f / osum[0];
  char* ep = (char*)lk + w * 4096;  // 32 rows(q) x 128B(d), swizzled
#pragma unroll
  for (int dt = 0; dt < 2; ++dt) {
#pragma unroll
    for (int rr = 0; rr < 4; ++rr) {
      const float a0 = (dt ? o1[4 * rr + 0] : o0[4 * rr + 0]) * inv;
      const float a1 = (dt ? o1[4 * rr + 1] : o0[4 * rr + 1]) * inv;
      const float a2 = (dt ? o1[4 * rr + 2] : o0[4 * rr + 2]) * inv;
      const float a3 = (dt ? o1[4 * rr + 3] : o0[4 * rr + 3]) * inv;
      const unsigned long long v =
          (unsigned long long)pk2(a0, a1) | ((unsigned long long)pk2(a2, a3) << 32);
      const int blk = 4 * dt + rr;
      *(unsigned long long*)(ep + lq * 128 + ((blk << 4) ^ swz) + 8 * hi) = v;
    }
  }
  __syncthreads();
#pragma unroll
  for (int i = 0; i < 4; ++i) {
    const int qq = 8 * i + (l >> 3);
    const u16x8 vv =
        *(const u16x8*)(ep + qq * 128 + (((l & 7) << 4) ^ ((qq & 7) << 4)));
    *(u16x8*)(Y + (size_t)(q0w + qq) * 1024 + h * 64 + (l & 7) * 8) = vv;
  }
}

// --------------------------- launcher --------------------------------------
extern "C" void kernel_launch(void* const* d_in, const int* in_sizes, int n_in,
                              void* d_out, int out_size, void* d_ws, size_t ws_size,
                              hipStream_t stream) {
  const float* x   = (const float*)d_in[0];
  const float* ve  = (const float*)d_in[1];
  const float* qw  = (const float*)d_in[2];
  const float* lam = (const float*)d_in[3];
  const float* pw  = (const float*)d_in[4];
  float* out = (float*)d_out;

  unsigned short* ws = (unsigned short*)d_ws;
  unsigned short* x_bf  = ws;                                // 4096*1024
  unsigned short* wqkv  = x_bf + (size_t)4096 * 1024;        // 3072*1024
  unsigned short* wproj = wqkv + (size_t)3072 * 1024;        // 1024*1024
  unsigned short* qkv   = wproj + (size_t)1024 * 1024;       // 4096*3072
  unsigned short* Qr    = qkv + (size_t)4096 * 3072;         // 16*4096*64
  unsigned short* Kr    = Qr + (size_t)4096 * 1024;
  unsigned short* Vm    = Kr + (size_t)4096 * 1024;
  unsigned short* VTt   = Vm + (size_t)4096 * 1024;
  unsigned short* Yb    = VTt + (size_t)4096 * 1024;
  float* ct = (float*)(Yb + (size_t)4096 * 1024);            // 4096*32
  float* st = ct + 4096 * 32;

  rope_tab<<<512, 256, 0, stream>>>(ct, st);
  cast_f2b8<<<2048, 256, 0, stream>>>(x, x_bf, 524288);
  cast_f2b8<<<1536, 256, 0, stream>>>(qw, wqkv, 393216);
  cast_f2b8<<<512, 256, 0, stream>>>(pw, wproj, 131072);
  gemm_bt<1><<<768, 256, 0, stream>>>(x_bf, wqkv, (void*)qkv, 4096, 3072, 1024);
  fuse_qkv<<<256, 256, 0, stream>>>(qkv, ve, lam, ct, st, Qr, Kr, Vm);
  transpose_v<<<1024, 256, 0, stream>>>(Vm, VTt);
  attn_fa<<<1024, 128, 0, stream>>>(Qr, Kr, VTt, Yb);
  gemm_bt<0><<<256, 256, 0, stream>>>(Yb, wproj, (void*)out, 4096, 1024, 1024);
}

// Round 5
// 243.407 us; speedup vs baseline: 1.0178x; 1.0178x over previous
//
#include <hip/hip_runtime.h>
#include <stdint.h>

// ---------------------------------------------------------------------------
// CausalSelfAttention (T=4096, DIM=1024, 16 heads x 64) on gfx950, bf16 MFMA.
// Pipeline: cast->bf16 | rope tables | GEMM1 qkv | fuse(vmix,rms,rope) |
//           transpose V | flash attention (swapped 32x32, intra-block
//           split-KV x4, reg-direct K/V, LDS merge) | GEMM2 -> fp32 out
// ---------------------------------------------------------------------------

typedef __attribute__((ext_vector_type(8))) __bf16 bf16x8;
typedef __attribute__((ext_vector_type(8))) unsigned short u16x8;
typedef __attribute__((ext_vector_type(4))) float f32x4;
typedef __attribute__((ext_vector_type(16))) float f32x16;

union U8 { u16x8 s; bf16x8 b; };
union PF { unsigned int u[4]; u16x8 s; bf16x8 b; };

__device__ __forceinline__ float bf2f(unsigned short u) {
  union { unsigned int i; float f; } c; c.i = ((unsigned int)u) << 16; return c.f;
}
__device__ __forceinline__ unsigned short f2bf(float f) {
  union { __bf16 h; unsigned short u; } c; c.h = (__bf16)f; return c.u;
}
__device__ __forceinline__ unsigned int pk2(float lo, float hi) {
  return (unsigned int)f2bf(lo) | ((unsigned int)f2bf(hi) << 16);
}

// async global->LDS, 16B per lane; LDS dest is wave-uniform base + lane*16
#define GLOAD16(gp, lp)                                                         \
  __builtin_amdgcn_global_load_lds(                                             \
      (const __attribute__((address_space(1))) void*)(gp),                      \
      (__attribute__((address_space(3))) void*)(lp), 16, 0, 0)

#define MFMA16(a, b, c) __builtin_amdgcn_mfma_f32_16x16x32_bf16((a), (b), (c), 0, 0, 0)
#define MFMA32(a, b, c) __builtin_amdgcn_mfma_f32_32x32x16_bf16((a), (b), (c), 0, 0, 0)

constexpr float ATTN_SCALE = 0.12f;
constexpr float LOG2E = 1.44269504088896340736f;
constexpr float QSCALE = ATTN_SCALE * LOG2E;  // folded into Q at fuse stage

// --------------------------- rope tables -----------------------------------
__global__ void rope_tab(float* __restrict__ ct, float* __restrict__ st) {
  const int i = blockIdx.x * 256 + threadIdx.x;
  if (i >= 4096 * 32) return;
  const int tt = i >> 5, k = i & 31;
  float cv = 1.0f, sv = 0.0f;
  if (k < 16) {
    const float af = powf(1.0f / 1024.0f, (float)k * (1.0f / 15.0f));
    const float th = (float)tt * af;
    cv = cosf(th);
    sv = sinf(th);
  }
  ct[i] = cv; st[i] = sv;
}

// --------------------------- f32 -> bf16 cast ------------------------------
__global__ void cast_f2b8(const float* __restrict__ in, unsigned short* __restrict__ out, int n8) {
  const int i = blockIdx.x * 256 + threadIdx.x;
  if (i >= n8) return;
  const float4 a = ((const float4*)in)[2 * i];
  const float4 b = ((const float4*)in)[2 * i + 1];
  u16x8 o;
  o[0] = f2bf(a.x); o[1] = f2bf(a.y); o[2] = f2bf(a.z); o[3] = f2bf(a.w);
  o[4] = f2bf(b.x); o[5] = f2bf(b.y); o[6] = f2bf(b.z); o[7] = f2bf(b.w);
  ((u16x8*)out)[i] = o;
}

// --------------------------- GEMM: C[M][N] = A[M][K] * B[N][K]^T -----------
template <int OUT_BF16>
__global__ __launch_bounds__(256) void gemm_bt(
    const unsigned short* __restrict__ A, const unsigned short* __restrict__ B,
    void* __restrict__ Cout, int M, int N, int K) {
  __shared__ unsigned short lA[128 * 32];
  __shared__ unsigned short lB[128 * 32];
  const int nbn = N >> 7;
  const int bm = blockIdx.x / nbn, bn = blockIdx.x % nbn;
  const int t = threadIdx.x;
  const int w = t >> 6, l = t & 63;
  const int g = l >> 4, c = l & 15;
  const int wr = (w >> 1) * 64, wc = (w & 1) * 64;

  const int srow = t >> 2;
  const int scol = ((t & 3) << 4) ^ ((srow & 3) << 4);  // byte col, XOR swizzle
  const char* ga = (const char*)(A + (size_t)(bm * 128 + srow) * K) + scol;
  const char* gb = (const char*)(B + (size_t)(bn * 128 + srow) * K) + scol;
  const size_t rowK2 = (size_t)64 * K * 2;
  char* la_dst = (char*)lA + t * 16;
  char* lb_dst = (char*)lB + t * 16;

  f32x4 acc[4][4] = {};

  for (int kt = 0; kt < K; kt += 32) {
    const char* gak = ga + (size_t)kt * 2;
    const char* gbk = gb + (size_t)kt * 2;
    GLOAD16(gak, la_dst);
    GLOAD16(gak + rowK2, la_dst + 4096);
    GLOAD16(gbk, lb_dst);
    GLOAD16(gbk + rowK2, lb_dst + 4096);
    __syncthreads();
    U8 af[4], bfr[4];
#pragma unroll
    for (int mi = 0; mi < 4; ++mi) {
      const int row = wr + 16 * mi + c;
      af[mi].s = *(const u16x8*)((const char*)lA + row * 64 + ((16 * g) ^ ((row & 3) << 4)));
    }
#pragma unroll
    for (int ni = 0; ni < 4; ++ni) {
      const int row = wc + 16 * ni + c;
      bfr[ni].s = *(const u16x8*)((const char*)lB + row * 64 + ((16 * g) ^ ((row & 3) << 4)));
    }
#pragma unroll
    for (int mi = 0; mi < 4; ++mi)
#pragma unroll
      for (int ni = 0; ni < 4; ++ni)
        acc[mi][ni] = MFMA16(af[mi].b, bfr[ni].b, acc[mi][ni]);
    __syncthreads();
  }
#pragma unroll
  for (int mi = 0; mi < 4; ++mi) {
#pragma unroll
    for (int ni = 0; ni < 4; ++ni) {
#pragma unroll
      for (int r = 0; r < 4; ++r) {
        const int row = bm * 128 + wr + 16 * mi + 4 * g + r;
        const int col = bn * 128 + wc + 16 * ni + c;
        const float v = acc[mi][ni][r];
        if (OUT_BF16)
          ((unsigned short*)Cout)[(size_t)row * N + col] = f2bf(v);
        else
          ((float*)Cout)[(size_t)row * N + col] = v;
      }
    }
  }
}

// --------------------------- fuse: vmix + rmsnorm + rope -------------------
__device__ __forceinline__ void load64f(const unsigned short* p, float* x) {
#pragma unroll
  for (int j = 0; j < 8; ++j) {
    const u16x8 v = *(const u16x8*)(p + 8 * j);
#pragma unroll
    for (int e = 0; e < 8; ++e) x[8 * j + e] = bf2f(v[e]);
  }
}

__device__ __forceinline__ void rmsrope_store(const float* x, const float* ct, const float* st,
                                              unsigned short* outp, float pscale) {
  float ms = 0.f;
#pragma unroll
  for (int j = 0; j < 64; ++j) ms += x[j] * x[j];
  const float sc = rsqrtf(ms * (1.0f / 64.0f) + 1.1920928955078125e-7f) * pscale;
  float y[64];
#pragma unroll
  for (int j = 0; j < 32; ++j) {
    const float cc = ct[j], ss = st[j];
    const float a = x[j] * sc, b = x[j + 32] * sc;
    y[j] = a * cc + b * ss;
    y[j + 32] = b * cc - a * ss;
  }
#pragma unroll
  for (int j = 0; j < 8; ++j) {
    u16x8 o;
#pragma unroll
    for (int e = 0; e < 8; ++e) o[e] = f2bf(y[8 * j + e]);
    *(u16x8*)(outp + 8 * j) = o;
  }
}

__global__ __launch_bounds__(256) void fuse_qkv(
    const unsigned short* __restrict__ qkv,  // [4096][3072] bf16
    const float* __restrict__ ve,            // [4096][1024]
    const float* __restrict__ lam,           // [2]
    const float* __restrict__ ct, const float* __restrict__ st,  // [4096][32]
    unsigned short* __restrict__ Qo,  // [16][4096][64]  (pre-scaled by QSCALE)
    unsigned short* __restrict__ Ko,  // [16][4096][64]
    unsigned short* __restrict__ Vo)  // [16][4096][64]
{
  const int gid = blockIdx.x * 256 + threadIdx.x;  // 65536 = 4096 t * 16 h
  const int tt = gid >> 4, h = gid & 15;
  const unsigned short* base = qkv + (size_t)tt * 3072 + h * 64;
  const float* ctp = ct + tt * 32;
  const float* stp = st + tt * 32;
  float x[64];
  load64f(base, x);
  rmsrope_store(x, ctp, stp, Qo + ((size_t)h * 4096 + tt) * 64, QSCALE);
  load64f(base + 1024, x);
  rmsrope_store(x, ctp, stp, Ko + ((size_t)h * 4096 + tt) * 64, 1.0f);
  const float l0 = lam[0], l1 = lam[1];
  const float* vp = ve + (size_t)tt * 1024 + h * 64;
  load64f(base + 2048, x);
  unsigned short* vo = Vo + ((size_t)h * 4096 + tt) * 64;
#pragma unroll
  for (int j = 0; j < 8; ++j) {
    u16x8 o;
#pragma unroll
    for (int e = 0; e < 8; ++e) o[e] = f2bf(l0 * x[8 * j + e] + l1 * vp[8 * j + e]);
    *(u16x8*)(vo + 8 * j) = o;
  }
}

// --------------------------- V transpose: [16][4096][64] -> [16][64][4096] -
__global__ __launch_bounds__(256) void transpose_v(const unsigned short* __restrict__ vin,
                                                   unsigned short* __restrict__ vout) {
  __shared__ unsigned short tile[64][72];
  const int h = (int)(blockIdx.x & 15), tb = (int)(blockIdx.x >> 4);
  const int t = threadIdx.x;
  const int r = t >> 2, c0 = (t & 3) * 16;
  const unsigned short* src = vin + ((size_t)h * 4096 + tb * 64 + r) * 64 + c0;
#pragma unroll
  for (int j = 0; j < 16; ++j) tile[c0 + j][r] = src[j];
  __syncthreads();
  unsigned short* dst = vout + ((size_t)h * 64 + r) * 4096 + tb * 64 + c0;
#pragma unroll
  for (int j = 0; j < 16; ++j) dst[j] = tile[r][c0 + j];
}

// --------------------------- flash attention -------------------------------
// block = (head, 32 q-rows), 4 waves; intra-block split-KV: wave w processes
// kv-tiles ti = w, w+4, ... with private (m, ls, O^T); merged once via LDS.
// No LDS / no barriers in the main loop: K/V fragments load global->VGPR
// (L2-resident; XCD-grouped head mapping keeps each head's 1MB in one L2).
// Swapped QK^T (S^T = mfma32(K,Q)): lane owns one q row; softmax lane-local.
// Row-sum via ones-MFMA; defer-max (THR=8) skips O-rescale on stable tiles.
__global__ __launch_bounds__(256, 3) void attn_fa(
    const unsigned short* __restrict__ Q,   // [16][4096][64] (scaled)
    const unsigned short* __restrict__ Kv,  // [16][4096][64]
    const unsigned short* __restrict__ VT,  // [16][64][4096]
    unsigned short* __restrict__ Y)         // [4096][1024]
{
  __shared__ float oL[4][64][33];   // per-wave partial O^T (padded: bank-safe)
  __shared__ float mlL[4][2][32];   // per-wave m / ls per q row

  const int b = (int)blockIdx.x;
  const int h = 2 * (b & 7) + ((b >> 3) & 1);  // same-h -> same XCD (b%8)
  const int qb = 127 - (b >> 4);               // longest first
  const int q0 = qb * 32;
  const int t = threadIdx.x;
  const int w = t >> 6, l = t & 63;
  const int lq = l & 31;    // this lane's q row
  const int hi = l >> 5;    // k/d half selector

  const unsigned short* kbase = Kv + (size_t)h * 262144;
  const unsigned short* vbase = VT + (size_t)h * 262144;

  // Q fragments (B operand): lane holds Q[q0+lq][16*dd + 8*hi .. +8]
  U8 qf[4];
  {
    const unsigned short* qp = Q + ((size_t)h * 4096 + q0 + lq) * 64 + 8 * hi;
#pragma unroll
    for (int dd = 0; dd < 4; ++dd) qf[dd].s = *(const u16x8*)(qp + 16 * dd);
  }

  U8 onesf;
#pragma unroll
  for (int e = 0; e < 8; ++e) onesf.s[e] = 0x3F80;  // bf16 1.0

  f32x16 o0 = {}, o1 = {};   // O^T: d rows 0-31 / 32-63, col q = lq
  f32x16 osum = {};          // row-sum accum (use [0])
  float m = -3e38f;

  const int ntiles = (32 * qb + 95) >> 6;

  for (int ti = w; ti < ntiles; ti += 4) {
    const int kv0 = ti << 6;
    const bool live1 = (kv0 + 32) <= (q0 + 31);

    // ---- K fragments (global->reg) + S^T = K * Q^T ----
    const unsigned short* kp = kbase + (size_t)(kv0 + lq) * 64 + 8 * hi;
    U8 kf0[4], kf1[4];
#pragma unroll
    for (int dd = 0; dd < 4; ++dd) kf0[dd].s = *(const u16x8*)(kp + 16 * dd);
    if (live1) {
#pragma unroll
      for (int dd = 0; dd < 4; ++dd) kf1[dd].s = *(const u16x8*)(kp + 2048 + 16 * dd);
    }
    __builtin_amdgcn_s_setprio(1);
    f32x16 s0 = {}, s1;
#pragma unroll
    for (int dd = 0; dd < 4; ++dd) s0 = MFMA32(kf0[dd].b, qf[dd].b, s0);
    if (live1) {
      f32x16 z = {};
#pragma unroll
      for (int dd = 0; dd < 4; ++dd) z = MFMA32(kf1[dd].b, qf[dd].b, z);
      s1 = z;
    } else {
#pragma unroll
      for (int e = 0; e < 16; ++e) s1[e] = -3e38f;
    }
    __builtin_amdgcn_s_setprio(0);

    // ---- causal mask (kv = kv0 + 32*st + (e&3)+8*(e>>2)+4*hi) ----
    const int thr0 = q0 + lq - kv0 - 4 * hi;
    if (kv0 + 31 > q0) {
#pragma unroll
      for (int e = 0; e < 16; ++e) {
        const int kvr = (e & 3) + 8 * (e >> 2);
        if (kvr > thr0) s0[e] = -3e38f;
      }
    }
    if (live1 && kv0 + 63 > q0) {
      const int thr1 = thr0 - 32;
#pragma unroll
      for (int e = 0; e < 16; ++e) {
        const int kvr = (e & 3) + 8 * (e >> 2);
        if (kvr > thr1) s1[e] = -3e38f;
      }
    }

    // ---- online softmax (per q row = per lane) ----
    float pm;
    {
      float t0 = fmaxf(s0[0], s0[1]), t1 = fmaxf(s0[2], s0[3]);
      float t2 = fmaxf(s0[4], s0[5]), t3 = fmaxf(s0[6], s0[7]);
      float t4 = fmaxf(s0[8], s0[9]), t5 = fmaxf(s0[10], s0[11]);
      float t6 = fmaxf(s0[12], s0[13]), t7 = fmaxf(s0[14], s0[15]);
      pm = fmaxf(fmaxf(fmaxf(t0, t1), fmaxf(t2, t3)),
                 fmaxf(fmaxf(t4, t5), fmaxf(t6, t7)));
      if (live1) {
        float v0 = fmaxf(s1[0], s1[1]), v1 = fmaxf(s1[2], s1[3]);
        float v2 = fmaxf(s1[4], s1[5]), v3 = fmaxf(s1[6], s1[7]);
        float v4 = fmaxf(s1[8], s1[9]), v5 = fmaxf(s1[10], s1[11]);
        float v6 = fmaxf(s1[12], s1[13]), v7 = fmaxf(s1[14], s1[15]);
        pm = fmaxf(pm, fmaxf(fmaxf(fmaxf(v0, v1), fmaxf(v2, v3)),
                             fmaxf(fmaxf(v4, v5), fmaxf(v6, v7))));
      }
    }
    pm = fmaxf(pm, __shfl_xor(pm, 32));
    if (!__all(pm <= m + 8.0f)) {
      const float mn = fmaxf(m, pm);
      const float alpha = exp2f(m - mn);
#pragma unroll
      for (int e = 0; e < 16; ++e) { o0[e] *= alpha; o1[e] *= alpha; }
      osum[0] *= alpha;
      m = mn;
    }
#pragma unroll
    for (int e = 0; e < 16; ++e) s0[e] = exp2f(s0[e] - m);
    if (live1) {
#pragma unroll
      for (int e = 0; e < 16; ++e) s1[e] = exp2f(s1[e] - m);
    }

    // ---- P^T pack + redistribute + PV (V frags global->reg) ----
    const unsigned short* vp = vbase + (size_t)lq * 4096 + kv0 + 8 * hi;
#define DO_SLAB(SV, B, KS)                                                       \
  do {                                                                           \
    const unsigned int ua = pk2(SV[8 * (B) + 0], SV[8 * (B) + 1]);               \
    const unsigned int ub = pk2(SV[8 * (B) + 2], SV[8 * (B) + 3]);               \
    const unsigned int uc = pk2(SV[8 * (B) + 4], SV[8 * (B) + 5]);               \
    const unsigned int ud = pk2(SV[8 * (B) + 6], SV[8 * (B) + 7]);               \
    const unsigned int sa = (unsigned int)__shfl_xor((int)ua, 32);               \
    const unsigned int sb = (unsigned int)__shfl_xor((int)ub, 32);               \
    const unsigned int sc = (unsigned int)__shfl_xor((int)uc, 32);               \
    const unsigned int sd = (unsigned int)__shfl_xor((int)ud, 32);               \
    PF pf;                                                                       \
    pf.u[0] = hi ? sc : ua;                                                      \
    pf.u[1] = hi ? sd : ub;                                                      \
    pf.u[2] = hi ? uc : sa;                                                      \
    pf.u[3] = hi ? ud : sb;                                                      \
    U8 vf0, vf1;                                                                 \
    vf0.s = *(const u16x8*)(vp + 16 * (KS));                                     \
    vf1.s = *(const u16x8*)(vp + 131072 + 16 * (KS));                            \
    __builtin_amdgcn_s_setprio(1);                                               \
    o0 = MFMA32(vf0.b, pf.b, o0);                                                \
    o1 = MFMA32(vf1.b, pf.b, o1);                                                \
    osum = MFMA32(onesf.b, pf.b, osum);                                          \
    __builtin_amdgcn_s_setprio(0);                                               \
  } while (0)

    DO_SLAB(s0, 0, 0);
    DO_SLAB(s0, 1, 1);
    if (live1) {
      DO_SLAB(s1, 0, 2);
      DO_SLAB(s1, 1, 3);
    }
#undef DO_SLAB
  }

  // ---- write per-wave partials ----
#pragma unroll
  for (int e = 0; e < 16; ++e) {
    const int d = (e & 3) + 8 * (e >> 2) + 4 * hi;
    oL[w][d][lq] = o0[e];
    oL[w][d + 32][lq] = o1[e];
  }
  if (hi == 0) { mlL[w][0][lq] = m; mlL[w][1][lq] = osum[0]; }
  __syncthreads();

  // ---- merge 4 partials; y = O / ls; coalesced bf16 store ----
  const int q = t >> 3, dblk = t & 7;
  const float m0 = mlL[0][0][q], m1 = mlL[1][0][q];
  const float m2 = mlL[2][0][q], m3 = mlL[3][0][q];
  const float mm = fmaxf(fmaxf(m0, m1), fmaxf(m2, m3));
  const float f0 = exp2f(m0 - mm), f1 = exp2f(m1 - mm);
  const float f2 = exp2f(m2 - mm), f3 = exp2f(m3 - mm);
  const float den = f0 * mlL[0][1][q] + f1 * mlL[1][1][q] +
                    f2 * mlL[2][1][q] + f3 * mlL[3][1][q];
  const float invd = 1.0f / den;
  u16x8 yv;
#pragma unroll
  for (int i = 0; i < 8; ++i) {
    const int d = dblk * 8 + i;
    const float a = f0 * oL[0][d][q] + f1 * oL[1][d][q] +
                    f2 * oL[2][d][q] + f3 * oL[3][d][q];
    yv[i] = f2bf(a * invd);
  }
  *(u16x8*)(Y + (size_t)(q0 + q) * 1024 + h * 64 + dblk * 8) = yv;
}

// --------------------------- launcher --------------------------------------
extern "C" void kernel_launch(void* const* d_in, const int* in_sizes, int n_in,
                              void* d_out, int out_size, void* d_ws, size_t ws_size,
                              hipStream_t stream) {
  const float* x   = (const float*)d_in[0];
  const float* ve  = (const float*)d_in[1];
  const float* qw  = (const float*)d_in[2];
  const float* lam = (const float*)d_in[3];
  const float* pw  = (const float*)d_in[4];
  float* out = (float*)d_out;

  unsigned short* ws = (unsigned short*)d_ws;
  unsigned short* x_bf  = ws;                                // 4096*1024
  unsigned short* wqkv  = x_bf + (size_t)4096 * 1024;        // 3072*1024
  unsigned short* wproj = wqkv + (size_t)3072 * 1024;        // 1024*1024
  unsigned short* qkv   = wproj + (size_t)1024 * 1024;       // 4096*3072
  unsigned short* Qr    = qkv + (size_t)4096 * 3072;         // 16*4096*64
  unsigned short* Kr    = Qr + (size_t)4096 * 1024;
  unsigned short* Vm    = Kr + (size_t)4096 * 1024;
  unsigned short* VTt   = Vm + (size_t)4096 * 1024;
  unsigned short* Yb    = VTt + (size_t)4096 * 1024;
  float* ct = (float*)(Yb + (size_t)4096 * 1024);            // 4096*32
  float* st = ct + 4096 * 32;

  rope_tab<<<512, 256, 0, stream>>>(ct, st);
  cast_f2b8<<<2048, 256, 0, stream>>>(x, x_bf, 524288);
  cast_f2b8<<<1536, 256, 0, stream>>>(qw, wqkv, 393216);
  cast_f2b8<<<512, 256, 0, stream>>>(pw, wproj, 131072);
  gemm_bt<1><<<768, 256, 0, stream>>>(x_bf, wqkv, (void*)qkv, 4096, 3072, 1024);
  fuse_qkv<<<256, 256, 0, stream>>>(qkv, ve, lam, ct, st, Qr, Kr, Vm);
  transpose_v<<<1024, 256, 0, stream>>>(Vm, VTt);
  attn_fa<<<2048, 256, 0, stream>>>(Qr, Kr, VTt, Yb);
  gemm_bt<0><<<256, 256, 0, stream>>>(Yb, wproj, (void*)out, 4096, 1024, 1024);
}

// Round 6
// 198.412 us; speedup vs baseline: 1.2486x; 1.2268x over previous
//
#include <hip/hip_runtime.h>
#include <stdint.h>

// ---------------------------------------------------------------------------
// CausalSelfAttention (T=4096, DIM=1024, 16 heads x 64) on gfx950, bf16 MFMA.
// Pipeline: cast->bf16 | rope tables | GEMM1 qkv | fuse(vmix,rms,rope) |
//           transpose V | flash attention (swapped 32x32, split-KV x4,
//           per-wave private LDS tiles, no main-loop barriers) | GEMM2
// ---------------------------------------------------------------------------

typedef __attribute__((ext_vector_type(8))) __bf16 bf16x8;
typedef __attribute__((ext_vector_type(8))) unsigned short u16x8;
typedef __attribute__((ext_vector_type(4))) float f32x4;
typedef __attribute__((ext_vector_type(16))) float f32x16;

union U8 { u16x8 s; bf16x8 b; };
union PF { unsigned int u[4]; u16x8 s; bf16x8 b; };

__device__ __forceinline__ float bf2f(unsigned short u) {
  union { unsigned int i; float f; } c; c.i = ((unsigned int)u) << 16; return c.f;
}
__device__ __forceinline__ unsigned short f2bf(float f) {
  union { __bf16 h; unsigned short u; } c; c.h = (__bf16)f; return c.u;
}
__device__ __forceinline__ unsigned int pk2(float lo, float hi) {
  return (unsigned int)f2bf(lo) | ((unsigned int)f2bf(hi) << 16);
}

// async global->LDS, 16B per lane; LDS dest is wave-uniform base + lane*16
#define GLOAD16(gp, lp)                                                         \
  __builtin_amdgcn_global_load_lds(                                             \
      (const __attribute__((address_space(1))) void*)(gp),                      \
      (__attribute__((address_space(3))) void*)(lp), 16, 0, 0)

#define MFMA16(a, b, c) __builtin_amdgcn_mfma_f32_16x16x32_bf16((a), (b), (c), 0, 0, 0)
#define MFMA32(a, b, c) __builtin_amdgcn_mfma_f32_32x32x16_bf16((a), (b), (c), 0, 0, 0)

constexpr float ATTN_SCALE = 0.12f;
constexpr float LOG2E = 1.44269504088896340736f;
constexpr float QSCALE = ATTN_SCALE * LOG2E;  // folded into Q at fuse stage

// --------------------------- rope tables -----------------------------------
__global__ void rope_tab(float* __restrict__ ct, float* __restrict__ st) {
  const int i = blockIdx.x * 256 + threadIdx.x;
  if (i >= 4096 * 32) return;
  const int tt = i >> 5, k = i & 31;
  float cv = 1.0f, sv = 0.0f;
  if (k < 16) {
    const float af = powf(1.0f / 1024.0f, (float)k * (1.0f / 15.0f));
    const float th = (float)tt * af;
    cv = cosf(th);
    sv = sinf(th);
  }
  ct[i] = cv; st[i] = sv;
}

// --------------------------- f32 -> bf16 cast ------------------------------
__global__ void cast_f2b8(const float* __restrict__ in, unsigned short* __restrict__ out, int n8) {
  const int i = blockIdx.x * 256 + threadIdx.x;
  if (i >= n8) return;
  const float4 a = ((const float4*)in)[2 * i];
  const float4 b = ((const float4*)in)[2 * i + 1];
  u16x8 o;
  o[0] = f2bf(a.x); o[1] = f2bf(a.y); o[2] = f2bf(a.z); o[3] = f2bf(a.w);
  o[4] = f2bf(b.x); o[5] = f2bf(b.y); o[6] = f2bf(b.z); o[7] = f2bf(b.w);
  ((u16x8*)out)[i] = o;
}

// --------------------------- GEMM: C[M][N] = A[M][K] * B[N][K]^T -----------
template <int OUT_BF16>
__global__ __launch_bounds__(256) void gemm_bt(
    const unsigned short* __restrict__ A, const unsigned short* __restrict__ B,
    void* __restrict__ Cout, int M, int N, int K) {
  __shared__ unsigned short lA[128 * 32];
  __shared__ unsigned short lB[128 * 32];
  const int nbn = N >> 7;
  const int bm = blockIdx.x / nbn, bn = blockIdx.x % nbn;
  const int t = threadIdx.x;
  const int w = t >> 6, l = t & 63;
  const int g = l >> 4, c = l & 15;
  const int wr = (w >> 1) * 64, wc = (w & 1) * 64;

  const int srow = t >> 2;
  const int scol = ((t & 3) << 4) ^ ((srow & 3) << 4);  // byte col, XOR swizzle
  const char* ga = (const char*)(A + (size_t)(bm * 128 + srow) * K) + scol;
  const char* gb = (const char*)(B + (size_t)(bn * 128 + srow) * K) + scol;
  const size_t rowK2 = (size_t)64 * K * 2;
  char* la_dst = (char*)lA + t * 16;
  char* lb_dst = (char*)lB + t * 16;

  f32x4 acc[4][4] = {};

  for (int kt = 0; kt < K; kt += 32) {
    const char* gak = ga + (size_t)kt * 2;
    const char* gbk = gb + (size_t)kt * 2;
    GLOAD16(gak, la_dst);
    GLOAD16(gak + rowK2, la_dst + 4096);
    GLOAD16(gbk, lb_dst);
    GLOAD16(gbk + rowK2, lb_dst + 4096);
    __syncthreads();
    U8 af[4], bfr[4];
#pragma unroll
    for (int mi = 0; mi < 4; ++mi) {
      const int row = wr + 16 * mi + c;
      af[mi].s = *(const u16x8*)((const char*)lA + row * 64 + ((16 * g) ^ ((row & 3) << 4)));
    }
#pragma unroll
    for (int ni = 0; ni < 4; ++ni) {
      const int row = wc + 16 * ni + c;
      bfr[ni].s = *(const u16x8*)((const char*)lB + row * 64 + ((16 * g) ^ ((row & 3) << 4)));
    }
#pragma unroll
    for (int mi = 0; mi < 4; ++mi)
#pragma unroll
      for (int ni = 0; ni < 4; ++ni)
        acc[mi][ni] = MFMA16(af[mi].b, bfr[ni].b, acc[mi][ni]);
    __syncthreads();
  }
#pragma unroll
  for (int mi = 0; mi < 4; ++mi) {
#pragma unroll
    for (int ni = 0; ni < 4; ++ni) {
#pragma unroll
      for (int r = 0; r < 4; ++r) {
        const int row = bm * 128 + wr + 16 * mi + 4 * g + r;
        const int col = bn * 128 + wc + 16 * ni + c;
        const float v = acc[mi][ni][r];
        if (OUT_BF16)
          ((unsigned short*)Cout)[(size_t)row * N + col] = f2bf(v);
        else
          ((float*)Cout)[(size_t)row * N + col] = v;
      }
    }
  }
}

// --------------------------- fuse: vmix + rmsnorm + rope -------------------
__device__ __forceinline__ void load64f(const unsigned short* p, float* x) {
#pragma unroll
  for (int j = 0; j < 8; ++j) {
    const u16x8 v = *(const u16x8*)(p + 8 * j);
#pragma unroll
    for (int e = 0; e < 8; ++e) x[8 * j + e] = bf2f(v[e]);
  }
}

__device__ __forceinline__ void rmsrope_store(const float* x, const float* ct, const float* st,
                                              unsigned short* outp, float pscale) {
  float ms = 0.f;
#pragma unroll
  for (int j = 0; j < 64; ++j) ms += x[j] * x[j];
  const float sc = rsqrtf(ms * (1.0f / 64.0f) + 1.1920928955078125e-7f) * pscale;
  float y[64];
#pragma unroll
  for (int j = 0; j < 32; ++j) {
    const float cc = ct[j], ss = st[j];
    const float a = x[j] * sc, b = x[j + 32] * sc;
    y[j] = a * cc + b * ss;
    y[j + 32] = b * cc - a * ss;
  }
#pragma unroll
  for (int j = 0; j < 8; ++j) {
    u16x8 o;
#pragma unroll
    for (int e = 0; e < 8; ++e) o[e] = f2bf(y[8 * j + e]);
    *(u16x8*)(outp + 8 * j) = o;
  }
}

__global__ __launch_bounds__(256) void fuse_qkv(
    const unsigned short* __restrict__ qkv,  // [4096][3072] bf16
    const float* __restrict__ ve,            // [4096][1024]
    const float* __restrict__ lam,           // [2]
    const float* __restrict__ ct, const float* __restrict__ st,  // [4096][32]
    unsigned short* __restrict__ Qo,  // [16][4096][64]  (pre-scaled by QSCALE)
    unsigned short* __restrict__ Ko,  // [16][4096][64]
    unsigned short* __restrict__ Vo)  // [16][4096][64]
{
  const int gid = blockIdx.x * 256 + threadIdx.x;  // 65536 = 4096 t * 16 h
  const int tt = gid >> 4, h = gid & 15;
  const unsigned short* base = qkv + (size_t)tt * 3072 + h * 64;
  const float* ctp = ct + tt * 32;
  const float* stp = st + tt * 32;
  float x[64];
  load64f(base, x);
  rmsrope_store(x, ctp, stp, Qo + ((size_t)h * 4096 + tt) * 64, QSCALE);
  load64f(base + 1024, x);
  rmsrope_store(x, ctp, stp, Ko + ((size_t)h * 4096 + tt) * 64, 1.0f);
  const float l0 = lam[0], l1 = lam[1];
  const float* vp = ve + (size_t)tt * 1024 + h * 64;
  load64f(base + 2048, x);
  unsigned short* vo = Vo + ((size_t)h * 4096 + tt) * 64;
#pragma unroll
  for (int j = 0; j < 8; ++j) {
    u16x8 o;
#pragma unroll
    for (int e = 0; e < 8; ++e) o[e] = f2bf(l0 * x[8 * j + e] + l1 * vp[8 * j + e]);
    *(u16x8*)(vo + 8 * j) = o;
  }
}

// --------------------------- V transpose: [16][4096][64] -> [16][64][4096] -
__global__ __launch_bounds__(256) void transpose_v(const unsigned short* __restrict__ vin,
                                                   unsigned short* __restrict__ vout) {
  __shared__ unsigned short tile[64][72];
  const int h = (int)(blockIdx.x & 15), tb = (int)(blockIdx.x >> 4);
  const int t = threadIdx.x;
  const int r = t >> 2, c0 = (t & 3) * 16;
  const unsigned short* src = vin + ((size_t)h * 4096 + tb * 64 + r) * 64 + c0;
#pragma unroll
  for (int j = 0; j < 16; ++j) tile[c0 + j][r] = src[j];
  __syncthreads();
  unsigned short* dst = vout + ((size_t)h * 64 + r) * 4096 + tb * 64 + c0;
#pragma unroll
  for (int j = 0; j < 16; ++j) dst[j] = tile[r][c0 + j];
}

// --------------------------- flash attention -------------------------------
// block = (head, 32 q-rows), 4 waves; split-KV: wave w owns kv-tiles
// ti = w, w+4, ... (KVBLK=32). Each wave stages ITS OWN K/V^T tile into a
// private 8KB LDS slot via coalesced global_load_lds (pre-swizzled source),
// so the main loop has NO barriers; ordering is wave-local s_waitcnt.
// Per tile: read all frags LDS->reg, then issue next tile's loads (latency
// hides under MFMA+softmax). Merge partials once at the end via LDS (aliased
// over the staging buffers after a barrier).
__global__ __launch_bounds__(256, 4) void attn_fa(
    const unsigned short* __restrict__ Q,   // [16][4096][64] (scaled)
    const unsigned short* __restrict__ Kv,  // [16][4096][64]
    const unsigned short* __restrict__ VT,  // [16][64][4096]
    unsigned short* __restrict__ Y)         // [4096][1024]
{
  __shared__ float oL[4][64][33];   // 33 KB merge array; ALIASED as staging
  __shared__ float mlL[4][2][32];   // per-wave m / ls per q row

  const int b = (int)blockIdx.x;
  const int h = 2 * (b & 7) + ((b >> 3) & 1);  // same-h -> same XCD (b%8)
  const int qb = 127 - (b >> 4);               // longest first
  const int q0 = qb * 32;
  const int t = threadIdx.x;
  const int w = t >> 6, l = t & 63;
  const int lq = l & 31;    // this lane's q row / kv row / d row
  const int hi = l >> 5;    // k half selector
  const int swz = (lq & 7) << 4;

  const unsigned short* kbase = Kv + (size_t)h * 262144;
  const unsigned short* vbase = VT + (size_t)h * 262144;

  // per-wave private staging slot: K [32][128B] + V^T [64][64B], XOR-swizzled
  char* Kw = (char*)oL + w * 8192;
  char* Vw = Kw + 4096;

  // staging lane mapping
  const int krow_l = l >> 3, kslot_l = l & 7;   // 8 lanes per 128B K row
  const int vrow_l = l >> 2, vslot_l = l & 3;   // 4 lanes per 64B  V row

#define STAGE(kv0)                                                               \
  do {                                                                           \
    _Pragma("unroll")                                                            \
    for (int cc = 0; cc < 4; ++cc) {                                             \
      const int r = 8 * cc + krow_l;                                             \
      GLOAD16(kbase + (size_t)((kv0) + r) * 64 + ((kslot_l ^ (r & 7)) << 3),     \
              Kw + cc * 1024 + l * 16);                                          \
      const int d = 16 * cc + vrow_l;                                            \
      GLOAD16(vbase + (size_t)d * 4096 + (kv0) + ((vslot_l ^ (d & 3)) << 3),     \
              Vw + cc * 1024 + l * 16);                                          \
    }                                                                            \
  } while (0)

  int ti = w;
  if (ti <= qb) STAGE(ti * 32);  // prologue stage; Q loads overlap its latency

  // Q fragments (B operand): lane holds Q[q0+lq][16*dd + 8*hi .. +8]
  U8 qf[4];
  {
    const unsigned short* qp = Q + ((size_t)h * 4096 + q0 + lq) * 64 + 8 * hi;
#pragma unroll
    for (int dd = 0; dd < 4; ++dd) qf[dd].s = *(const u16x8*)(qp + 16 * dd);
  }

  U8 onesf;
#pragma unroll
  for (int e = 0; e < 8; ++e) onesf.s[e] = 0x3F80;  // bf16 1.0

  f32x16 o0 = {}, o1 = {};   // O^T: d rows 0-31 / 32-63, col q = lq
  f32x16 osum = {};          // row-sum accum (use [0])
  float m = -3e38f;

  for (; ti <= qb; ti += 4) {
    const int kv0 = ti * 32;
    asm volatile("s_waitcnt vmcnt(0)" ::: "memory");  // my tile is in LDS

    // ---- all frag reads LDS->reg (K: 4, V: 4) ----
    U8 kf[4], vf[2][2];
#pragma unroll
    for (int dd = 0; dd < 4; ++dd)
      kf[dd].s = *(const u16x8*)(Kw + lq * 128 + ((32 * dd + 16 * hi) ^ swz));
#pragma unroll
    for (int ks = 0; ks < 2; ++ks) {
      vf[ks][0].s = *(const u16x8*)(Vw + lq * 64 + ((32 * ks + 16 * hi) ^ ((lq & 3) << 4)));
      const int d1 = lq + 32;
      vf[ks][1].s = *(const u16x8*)(Vw + d1 * 64 + ((32 * ks + 16 * hi) ^ ((d1 & 3) << 4)));
    }
    asm volatile("s_waitcnt lgkmcnt(0)" ::: "memory");  // reads done: slot free
    __builtin_amdgcn_sched_barrier(0);
    if (ti + 4 <= qb) STAGE((ti + 4) * 32);  // prefetch: hides under compute

    // ---- S^T = K * Q^T (32 kv x 32 q) ----
    __builtin_amdgcn_s_setprio(1);
    f32x16 s0 = {};
#pragma unroll
    for (int dd = 0; dd < 4; ++dd) s0 = MFMA32(kf[dd].b, qf[dd].b, s0);
    __builtin_amdgcn_s_setprio(0);

    // ---- causal mask (diagonal tile only): kv = kvr + 4*hi, q = lq ----
    if (ti == qb) {
      const int thr0 = lq - 4 * hi;
#pragma unroll
      for (int e = 0; e < 16; ++e) {
        const int kvr = (e & 3) + 8 * (e >> 2);
        if (kvr > thr0) s0[e] = -3e38f;
      }
    }

    // ---- online softmax (per q row = per lane) ----
    float pm;
    {
      float t0 = fmaxf(s0[0], s0[1]), t1 = fmaxf(s0[2], s0[3]);
      float t2 = fmaxf(s0[4], s0[5]), t3 = fmaxf(s0[6], s0[7]);
      float t4 = fmaxf(s0[8], s0[9]), t5 = fmaxf(s0[10], s0[11]);
      float t6 = fmaxf(s0[12], s0[13]), t7 = fmaxf(s0[14], s0[15]);
      pm = fmaxf(fmaxf(fmaxf(t0, t1), fmaxf(t2, t3)),
                 fmaxf(fmaxf(t4, t5), fmaxf(t6, t7)));
    }
    pm = fmaxf(pm, __shfl_xor(pm, 32));
    if (!__all(pm <= m + 8.0f)) {  // defer-max: rescale only on real growth
      const float mn = fmaxf(m, pm);
      const float alpha = exp2f(m - mn);
#pragma unroll
      for (int e = 0; e < 16; ++e) { o0[e] *= alpha; o1[e] *= alpha; }
      osum[0] *= alpha;
      m = mn;
    }
#pragma unroll
    for (int e = 0; e < 16; ++e) s0[e] = exp2f(s0[e] - m);

    // ---- P^T pack + cross-half redistribute + PV ----
#define DO_SLAB(KS)                                                              \
  do {                                                                           \
    const unsigned int ua = pk2(s0[8 * (KS) + 0], s0[8 * (KS) + 1]);             \
    const unsigned int ub = pk2(s0[8 * (KS) + 2], s0[8 * (KS) + 3]);             \
    const unsigned int uc = pk2(s0[8 * (KS) + 4], s0[8 * (KS) + 5]);             \
    const unsigned int ud = pk2(s0[8 * (KS) + 6], s0[8 * (KS) + 7]);             \
    const unsigned int sa = (unsigned int)__shfl_xor((int)ua, 32);               \
    const unsigned int sb = (unsigned int)__shfl_xor((int)ub, 32);               \
    const unsigned int sc = (unsigned int)__shfl_xor((int)uc, 32);               \
    const unsigned int sd = (unsigned int)__shfl_xor((int)ud, 32);               \
    PF pf;                                                                       \
    pf.u[0] = hi ? sc : ua;                                                      \
    pf.u[1] = hi ? sd : ub;                                                      \
    pf.u[2] = hi ? uc : sa;                                                      \
    pf.u[3] = hi ? ud : sb;                                                      \
    __builtin_amdgcn_s_setprio(1);                                               \
    o0 = MFMA32(vf[KS][0].b, pf.b, o0);                                          \
    o1 = MFMA32(vf[KS][1].b, pf.b, o1);                                          \
    osum = MFMA32(onesf.b, pf.b, osum);                                          \
    __builtin_amdgcn_s_setprio(0);                                               \
  } while (0)

    DO_SLAB(0);
    DO_SLAB(1);
#undef DO_SLAB
  }
#undef STAGE

  // ---- merge: all waves done -> staging LDS reusable as oL ----
  __syncthreads();
#pragma unroll
  for (int e = 0; e < 16; ++e) {
    const int d = (e & 3) + 8 * (e >> 2) + 4 * hi;
    oL[w][d][lq] = o0[e];
    oL[w][d + 32][lq] = o1[e];
  }
  if (hi == 0) { mlL[w][0][lq] = m; mlL[w][1][lq] = osum[0]; }
  __syncthreads();

  const int q = t >> 3, dblk = t & 7;
  const float m0 = mlL[0][0][q], m1 = mlL[1][0][q];
  const float m2 = mlL[2][0][q], m3 = mlL[3][0][q];
  const float mm = fmaxf(fmaxf(m0, m1), fmaxf(m2, m3));
  const float f0 = exp2f(m0 - mm), f1 = exp2f(m1 - mm);
  const float f2 = exp2f(m2 - mm), f3 = exp2f(m3 - mm);
  const float den = f0 * mlL[0][1][q] + f1 * mlL[1][1][q] +
                    f2 * mlL[2][1][q] + f3 * mlL[3][1][q];
  const float invd = 1.0f / den;
  u16x8 yv;
#pragma unroll
  for (int i = 0; i < 8; ++i) {
    const int d = dblk * 8 + i;
    const float a = f0 * oL[0][d][q] + f1 * oL[1][d][q] +
                    f2 * oL[2][d][q] + f3 * oL[3][d][q];
    yv[i] = f2bf(a * invd);
  }
  *(u16x8*)(Y + (size_t)(q0 + q) * 1024 + h * 64 + dblk * 8) = yv;
}

// --------------------------- launcher --------------------------------------
extern "C" void kernel_launch(void* const* d_in, const int* in_sizes, int n_in,
                              void* d_out, int out_size, void* d_ws, size_t ws_size,
                              hipStream_t stream) {
  const float* x   = (const float*)d_in[0];
  const float* ve  = (const float*)d_in[1];
  const float* qw  = (const float*)d_in[2];
  const float* lam = (const float*)d_in[3];
  const float* pw  = (const float*)d_in[4];
  float* out = (float*)d_out;

  unsigned short* ws = (unsigned short*)d_ws;
  unsigned short* x_bf  = ws;                                // 4096*1024
  unsigned short* wqkv  = x_bf + (size_t)4096 * 1024;        // 3072*1024
  unsigned short* wproj = wqkv + (size_t)3072 * 1024;        // 1024*1024
  unsigned short* qkv   = wproj + (size_t)1024 * 1024;       // 4096*3072
  unsigned short* Qr    = qkv + (size_t)4096 * 3072;         // 16*4096*64
  unsigned short* Kr    = Qr + (size_t)4096 * 1024;
  unsigned short* Vm    = Kr + (size_t)4096 * 1024;
  unsigned short* VTt   = Vm + (size_t)4096 * 1024;
  unsigned short* Yb    = VTt + (size_t)4096 * 1024;
  float* ct = (float*)(Yb + (size_t)4096 * 1024);            // 4096*32
  float* st = ct + 4096 * 32;

  rope_tab<<<512, 256, 0, stream>>>(ct, st);
  cast_f2b8<<<2048, 256, 0, stream>>>(x, x_bf, 524288);
  cast_f2b8<<<1536, 256, 0, stream>>>(qw, wqkv, 393216);
  cast_f2b8<<<512, 256, 0, stream>>>(pw, wproj, 131072);
  gemm_bt<1><<<768, 256, 0, stream>>>(x_bf, wqkv, (void*)qkv, 4096, 3072, 1024);
  fuse_qkv<<<256, 256, 0, stream>>>(qkv, ve, lam, ct, st, Qr, Kr, Vm);
  transpose_v<<<1024, 256, 0, stream>>>(Vm, VTt);
  attn_fa<<<2048, 256, 0, stream>>>(Qr, Kr, VTt, Yb);
  gemm_bt<0><<<256, 256, 0, stream>>>(Yb, wproj, (void*)out, 4096, 1024, 1024);
}

// Round 7
// 173.786 us; speedup vs baseline: 1.4255x; 1.1417x over previous
//
#include <hip/hip_runtime.h>
#include <stdint.h>

// ---------------------------------------------------------------------------
// CausalSelfAttention (T=4096, DIM=1024, 16 heads x 64) on gfx950, bf16 MFMA.
// Pipeline: cast->bf16 | rope tables | GEMM1 qkv | fuse(vmix,rms,rope ->
//           BLOCKED fragment-ordered Q/K) | transpose V -> BLOCKED V |
//           flash attention (swapped 32x32, split-KV x4, direct coalesced
//           fragment loads, zero main-loop LDS) | GEMM2 -> fp32 out
//
// Blocked layout: per (head, 32-kv tile) 4KB block; fragment r of lane l at
// byte r*1024 + l*16. Fragment loads are then plain global_load_dwordx4,
// perfectly coalesced (1KB/inst), L2-resident. No LDS staging needed at all.
// ---------------------------------------------------------------------------

typedef __attribute__((ext_vector_type(8))) __bf16 bf16x8;
typedef __attribute__((ext_vector_type(8))) unsigned short u16x8;
typedef __attribute__((ext_vector_type(4))) float f32x4;
typedef __attribute__((ext_vector_type(16))) float f32x16;

union U8 { u16x8 s; bf16x8 b; };
union PF { unsigned int u[4]; u16x8 s; bf16x8 b; };

__device__ __forceinline__ float bf2f(unsigned short u) {
  union { unsigned int i; float f; } c; c.i = ((unsigned int)u) << 16; return c.f;
}
__device__ __forceinline__ unsigned short f2bf(float f) {
  union { __bf16 h; unsigned short u; } c; c.h = (__bf16)f; return c.u;
}
__device__ __forceinline__ unsigned int pk2(float lo, float hi) {
  return (unsigned int)f2bf(lo) | ((unsigned int)f2bf(hi) << 16);
}

// async global->LDS, 16B per lane (GEMM staging only)
#define GLOAD16(gp, lp)                                                         \
  __builtin_amdgcn_global_load_lds(                                             \
      (const __attribute__((address_space(1))) void*)(gp),                      \
      (__attribute__((address_space(3))) void*)(lp), 16, 0, 0)

#define MFMA16(a, b, c) __builtin_amdgcn_mfma_f32_16x16x32_bf16((a), (b), (c), 0, 0, 0)
#define MFMA32(a, b, c) __builtin_amdgcn_mfma_f32_32x32x16_bf16((a), (b), (c), 0, 0, 0)

constexpr float ATTN_SCALE = 0.12f;
constexpr float LOG2E = 1.44269504088896340736f;
constexpr float QSCALE = ATTN_SCALE * LOG2E;  // folded into Q at fuse stage

// --------------------------- rope tables -----------------------------------
__global__ void rope_tab(float* __restrict__ ct, float* __restrict__ st) {
  const int i = blockIdx.x * 256 + threadIdx.x;
  if (i >= 4096 * 32) return;
  const int tt = i >> 5, k = i & 31;
  float cv = 1.0f, sv = 0.0f;
  if (k < 16) {
    const float af = powf(1.0f / 1024.0f, (float)k * (1.0f / 15.0f));
    const float th = (float)tt * af;
    cv = cosf(th);
    sv = sinf(th);
  }
  ct[i] = cv; st[i] = sv;
}

// --------------------------- f32 -> bf16 cast ------------------------------
__global__ void cast_f2b8(const float* __restrict__ in, unsigned short* __restrict__ out, int n8) {
  const int i = blockIdx.x * 256 + threadIdx.x;
  if (i >= n8) return;
  const float4 a = ((const float4*)in)[2 * i];
  const float4 b = ((const float4*)in)[2 * i + 1];
  u16x8 o;
  o[0] = f2bf(a.x); o[1] = f2bf(a.y); o[2] = f2bf(a.z); o[3] = f2bf(a.w);
  o[4] = f2bf(b.x); o[5] = f2bf(b.y); o[6] = f2bf(b.z); o[7] = f2bf(b.w);
  ((u16x8*)out)[i] = o;
}

// --------------------------- GEMM: C[M][N] = A[M][K] * B[N][K]^T -----------
template <int OUT_BF16>
__global__ __launch_bounds__(256) void gemm_bt(
    const unsigned short* __restrict__ A, const unsigned short* __restrict__ B,
    void* __restrict__ Cout, int M, int N, int K) {
  __shared__ unsigned short lA[128 * 32];
  __shared__ unsigned short lB[128 * 32];
  const int nbn = N >> 7;
  const int bm = blockIdx.x / nbn, bn = blockIdx.x % nbn;
  const int t = threadIdx.x;
  const int w = t >> 6, l = t & 63;
  const int g = l >> 4, c = l & 15;
  const int wr = (w >> 1) * 64, wc = (w & 1) * 64;

  const int srow = t >> 2;
  const int scol = ((t & 3) << 4) ^ ((srow & 3) << 4);  // byte col, XOR swizzle
  const char* ga = (const char*)(A + (size_t)(bm * 128 + srow) * K) + scol;
  const char* gb = (const char*)(B + (size_t)(bn * 128 + srow) * K) + scol;
  const size_t rowK2 = (size_t)64 * K * 2;
  char* la_dst = (char*)lA + t * 16;
  char* lb_dst = (char*)lB + t * 16;

  f32x4 acc[4][4] = {};

  for (int kt = 0; kt < K; kt += 32) {
    const char* gak = ga + (size_t)kt * 2;
    const char* gbk = gb + (size_t)kt * 2;
    GLOAD16(gak, la_dst);
    GLOAD16(gak + rowK2, la_dst + 4096);
    GLOAD16(gbk, lb_dst);
    GLOAD16(gbk + rowK2, lb_dst + 4096);
    __syncthreads();
    U8 af[4], bfr[4];
#pragma unroll
    for (int mi = 0; mi < 4; ++mi) {
      const int row = wr + 16 * mi + c;
      af[mi].s = *(const u16x8*)((const char*)lA + row * 64 + ((16 * g) ^ ((row & 3) << 4)));
    }
#pragma unroll
    for (int ni = 0; ni < 4; ++ni) {
      const int row = wc + 16 * ni + c;
      bfr[ni].s = *(const u16x8*)((const char*)lB + row * 64 + ((16 * g) ^ ((row & 3) << 4)));
    }
#pragma unroll
    for (int mi = 0; mi < 4; ++mi)
#pragma unroll
      for (int ni = 0; ni < 4; ++ni)
        acc[mi][ni] = MFMA16(af[mi].b, bfr[ni].b, acc[mi][ni]);
    __syncthreads();
  }
#pragma unroll
  for (int mi = 0; mi < 4; ++mi) {
#pragma unroll
    for (int ni = 0; ni < 4; ++ni) {
#pragma unroll
      for (int r = 0; r < 4; ++r) {
        const int row = bm * 128 + wr + 16 * mi + 4 * g + r;
        const int col = bn * 128 + wc + 16 * ni + c;
        const float v = acc[mi][ni][r];
        if (OUT_BF16)
          ((unsigned short*)Cout)[(size_t)row * N + col] = f2bf(v);
        else
          ((float*)Cout)[(size_t)row * N + col] = v;
      }
    }
  }
}

// --------------------------- fuse: vmix + rmsnorm + rope -------------------
__device__ __forceinline__ void load64f(const unsigned short* p, float* x) {
#pragma unroll
  for (int j = 0; j < 8; ++j) {
    const u16x8 v = *(const u16x8*)(p + 8 * j);
#pragma unroll
    for (int e = 0; e < 8; ++e) x[8 * j + e] = bf2f(v[e]);
  }
}

// store into blocked layout: chunk j (8 elems) at outp + 256*j
__device__ __forceinline__ void rmsrope_store_blk(const float* x, const float* ct,
                                                  const float* st, unsigned short* outp,
                                                  float pscale) {
  float ms = 0.f;
#pragma unroll
  for (int j = 0; j < 64; ++j) ms += x[j] * x[j];
  const float sc = rsqrtf(ms * (1.0f / 64.0f) + 1.1920928955078125e-7f) * pscale;
  float y[64];
#pragma unroll
  for (int j = 0; j < 32; ++j) {
    const float cc = ct[j], ss = st[j];
    const float a = x[j] * sc, b = x[j + 32] * sc;
    y[j] = a * cc + b * ss;
    y[j + 32] = b * cc - a * ss;
  }
#pragma unroll
  for (int j = 0; j < 8; ++j) {
    u16x8 o;
#pragma unroll
    for (int e = 0; e < 8; ++e) o[e] = f2bf(y[8 * j + e]);
    *(u16x8*)(outp + 256 * j) = o;
  }
}

__global__ __launch_bounds__(256) void fuse_qkv(
    const unsigned short* __restrict__ qkv,  // [4096][3072] bf16
    const float* __restrict__ ve,            // [4096][1024]
    const float* __restrict__ lam,           // [2]
    const float* __restrict__ ct, const float* __restrict__ st,  // [4096][32]
    unsigned short* __restrict__ Qb,  // blocked [16][128 tiles][2048]
    unsigned short* __restrict__ Kb,  // blocked
    unsigned short* __restrict__ Vm)  // flat [16][4096][64] (pre-transpose)
{
  const int gid = blockIdx.x * 256 + threadIdx.x;  // h-major: coalesced writes
  const int h = gid >> 12, tt = gid & 4095;
  const unsigned short* base = qkv + (size_t)tt * 3072 + h * 64;
  const float* ctp = ct + tt * 32;
  const float* stp = st + tt * 32;
  const size_t blk = (size_t)h * 262144 + (tt >> 5) * 2048 + (tt & 31) * 8;
  float x[64];
  load64f(base, x);
  rmsrope_store_blk(x, ctp, stp, Qb + blk, QSCALE);
  load64f(base + 1024, x);
  rmsrope_store_blk(x, ctp, stp, Kb + blk, 1.0f);
  const float l0 = lam[0], l1 = lam[1];
  const float* vp = ve + (size_t)tt * 1024 + h * 64;
  load64f(base + 2048, x);
  unsigned short* vo = Vm + ((size_t)h * 4096 + tt) * 64;
#pragma unroll
  for (int j = 0; j < 8; ++j) {
    u16x8 o;
#pragma unroll
    for (int e = 0; e < 8; ++e) o[e] = f2bf(l0 * x[8 * j + e] + l1 * vp[8 * j + e]);
    *(u16x8*)(vo + 8 * j) = o;
  }
}

// --------------------------- V transpose -> blocked V^T --------------------
// Vm [16][4096][64] -> Vb blocked: tile ti (32 kv), fragment r (ks=r>>1,
// half=r&1), lane l (hi=l>>5, lq=l&31) at elem ti*2048 + r*512 + l*8 holds
// V^T[d = lq+32*half][kv = 32*ti + 16*ks + 8*hi + j], j=0..7.
__global__ __launch_bounds__(256) void transpose_v(const unsigned short* __restrict__ vin,
                                                   unsigned short* __restrict__ vout) {
  __shared__ unsigned short tile[64][66];  // [d][kv], pad 66: conflict-free cols
  const int h = (int)(blockIdx.x & 15), tb = (int)(blockIdx.x >> 4);  // 64 kv rows
  const int t = threadIdx.x;
  const int r = t >> 2, c0 = (t & 3) * 16;
  const unsigned short* src = vin + ((size_t)h * 4096 + tb * 64 + r) * 64 + c0;
#pragma unroll
  for (int j = 0; j < 16; ++j) tile[c0 + j][r] = src[j];  // transpose scatter
  __syncthreads();
#pragma unroll
  for (int s = 0; s < 2; ++s) {  // 2 tiles per block
    const int rr = (t >> 6) & 3;
    const int ll = t & 63;
    const int hh = ll >> 5, qq = ll & 31;
    const int d = qq + 32 * (rr & 1);
    const int kvc = 32 * s + 16 * (rr >> 1) + 8 * hh;
    const u16x8 v = *(const u16x8*)&tile[d][kvc];
    *(u16x8*)(vout + (size_t)h * 262144 + (2 * tb + s) * 2048 + rr * 512 + hh * 256 + qq * 8) = v;
  }
}

// --------------------------- flash attention -------------------------------
// block = (head, 32 q-rows), 4 waves; split-KV: wave w owns kv-tiles
// ti = w, w+4, ... (KVBLK=32), private (m, ls, O^T), merged once via LDS.
// All K/V/Q fragment loads are direct, coalesced global_load_dwordx4 from the
// blocked layouts (base + l*16 + imm). Zero LDS / zero barriers in main loop.
// Swapped QK^T (S^T = mfma32(K,Q)): lane owns one q row; softmax lane-local
// (+1 shfl across halves); defer-max skips O-rescale on stable tiles.
__global__ __launch_bounds__(256, 4) void attn_fa(
    const unsigned short* __restrict__ Qb,  // blocked (scaled)
    const unsigned short* __restrict__ Kb,  // blocked
    const unsigned short* __restrict__ Vb,  // blocked V^T
    unsigned short* __restrict__ Y)         // [4096][1024]
{
  __shared__ float oL[4][64][33];   // per-wave partial O^T
  __shared__ float mlL[4][2][32];   // per-wave m / ls per q row

  const int b = (int)blockIdx.x;
  const int h = 2 * (b & 7) + ((b >> 3) & 1);  // same-h -> same XCD (b%8)
  const int qb = 127 - (b >> 4);               // longest first
  const int q0 = qb * 32;
  const int t = threadIdx.x;
  const int w = t >> 6, l = t & 63;
  const int lq = l & 31;    // this lane's q row
  const int hi = l >> 5;    // k/kv half selector

  const unsigned short* kh = Kb + (size_t)h * 262144 + l * 8;
  const unsigned short* vh = Vb + (size_t)h * 262144 + l * 8;

  // Q fragments: blocked tile qb
  U8 qf[4];
  {
    const unsigned short* qp = Qb + (size_t)h * 262144 + qb * 2048 + l * 8;
#pragma unroll
    for (int dd = 0; dd < 4; ++dd) qf[dd].s = *(const u16x8*)(qp + dd * 512);
  }

  f32x16 o0 = {}, o1 = {};   // O^T: d rows 0-31 / 32-63, col q = lq
  float osum = 0.0f, m = -3e38f;

  for (int ti = w; ti <= qb; ti += 4) {
    const unsigned short* kp = kh + ti * 2048;
    const unsigned short* vp = vh + ti * 2048;
    U8 kf[4], vf[4];
#pragma unroll
    for (int dd = 0; dd < 4; ++dd) kf[dd].s = *(const u16x8*)(kp + dd * 512);
#pragma unroll
    for (int r = 0; r < 4; ++r) vf[r].s = *(const u16x8*)(vp + r * 512);

    // ---- S^T = K * Q^T (32 kv x 32 q) ----
    __builtin_amdgcn_s_setprio(1);
    f32x16 s0 = {};
#pragma unroll
    for (int dd = 0; dd < 4; ++dd) s0 = MFMA32(kf[dd].b, qf[dd].b, s0);
    __builtin_amdgcn_s_setprio(0);

    // ---- causal mask (diagonal tile only): kv = kvr + 4*hi, q = lq ----
    if (ti == qb) {
      const int thr0 = lq - 4 * hi;
#pragma unroll
      for (int e = 0; e < 16; ++e) {
        const int kvr = (e & 3) + 8 * (e >> 2);
        if (kvr > thr0) s0[e] = -3e38f;
      }
    }

    // ---- online softmax (per q row = per lane) ----
    float pm;
    {
      float t0 = fmaxf(s0[0], s0[1]), t1 = fmaxf(s0[2], s0[3]);
      float t2 = fmaxf(s0[4], s0[5]), t3 = fmaxf(s0[6], s0[7]);
      float t4 = fmaxf(s0[8], s0[9]), t5 = fmaxf(s0[10], s0[11]);
      float t6 = fmaxf(s0[12], s0[13]), t7 = fmaxf(s0[14], s0[15]);
      pm = fmaxf(fmaxf(fmaxf(t0, t1), fmaxf(t2, t3)),
                 fmaxf(fmaxf(t4, t5), fmaxf(t6, t7)));
    }
    pm = fmaxf(pm, __shfl_xor(pm, 32));
    if (!__all(pm <= m + 8.0f)) {  // defer-max: rescale only on real growth
      const float mn = fmaxf(m, pm);
      const float alpha = exp2f(m - mn);
#pragma unroll
      for (int e = 0; e < 16; ++e) { o0[e] *= alpha; o1[e] *= alpha; }
      osum *= alpha;
      m = mn;
    }
#pragma unroll
    for (int e = 0; e < 16; ++e) s0[e] = exp2f(s0[e] - m);
    // pairwise-tree row sum + cross-half combine
    {
      const float a0 = (s0[0] + s0[1]) + (s0[2] + s0[3]);
      const float a1 = (s0[4] + s0[5]) + (s0[6] + s0[7]);
      const float a2 = (s0[8] + s0[9]) + (s0[10] + s0[11]);
      const float a3 = (s0[12] + s0[13]) + (s0[14] + s0[15]);
      float rs = (a0 + a1) + (a2 + a3);
      rs += __shfl_xor(rs, 32);
      osum += rs;
    }

    // ---- P^T pack + cross-half redistribute + PV ----
#define DO_SLAB(KS)                                                              \
  do {                                                                           \
    const unsigned int ua = pk2(s0[8 * (KS) + 0], s0[8 * (KS) + 1]);             \
    const unsigned int ub = pk2(s0[8 * (KS) + 2], s0[8 * (KS) + 3]);             \
    const unsigned int uc = pk2(s0[8 * (KS) + 4], s0[8 * (KS) + 5]);             \
    const unsigned int ud = pk2(s0[8 * (KS) + 6], s0[8 * (KS) + 7]);             \
    const unsigned int sa = (unsigned int)__shfl_xor((int)ua, 32);               \
    const unsigned int sb = (unsigned int)__shfl_xor((int)ub, 32);               \
    const unsigned int sc = (unsigned int)__shfl_xor((int)uc, 32);               \
    const unsigned int sd = (unsigned int)__shfl_xor((int)ud, 32);               \
    PF pf;                                                                       \
    pf.u[0] = hi ? sc : ua;                                                      \
    pf.u[1] = hi ? sd : ub;                                                      \
    pf.u[2] = hi ? uc : sa;                                                      \
    pf.u[3] = hi ? ud : sb;                                                      \
    __builtin_amdgcn_s_setprio(1);                                               \
    o0 = MFMA32(vf[2 * (KS)].b, pf.b, o0);                                       \
    o1 = MFMA32(vf[2 * (KS) + 1].b, pf.b, o1);                                   \
    __builtin_amdgcn_s_setprio(0);                                               \
  } while (0)

    DO_SLAB(0);
    DO_SLAB(1);
#undef DO_SLAB
  }

  // ---- merge 4 per-wave partials via LDS ----
#pragma unroll
  for (int e = 0; e < 16; ++e) {
    const int d = (e & 3) + 8 * (e >> 2) + 4 * hi;
    oL[w][d][lq] = o0[e];
    oL[w][d + 32][lq] = o1[e];
  }
  if (hi == 0) { mlL[w][0][lq] = m; mlL[w][1][lq] = osum; }
  __syncthreads();

  const int q = t >> 3, dblk = t & 7;
  const float m0 = mlL[0][0][q], m1 = mlL[1][0][q];
  const float m2 = mlL[2][0][q], m3 = mlL[3][0][q];
  const float mm = fmaxf(fmaxf(m0, m1), fmaxf(m2, m3));
  const float f0 = exp2f(m0 - mm), f1 = exp2f(m1 - mm);
  const float f2 = exp2f(m2 - mm), f3 = exp2f(m3 - mm);
  const float den = f0 * mlL[0][1][q] + f1 * mlL[1][1][q] +
                    f2 * mlL[2][1][q] + f3 * mlL[3][1][q];
  const float invd = 1.0f / den;
  u16x8 yv;
#pragma unroll
  for (int i = 0; i < 8; ++i) {
    const int d = dblk * 8 + i;
    const float a = f0 * oL[0][d][q] + f1 * oL[1][d][q] +
                    f2 * oL[2][d][q] + f3 * oL[3][d][q];
    yv[i] = f2bf(a * invd);
  }
  *(u16x8*)(Y + (size_t)(q0 + q) * 1024 + h * 64 + dblk * 8) = yv;
}

// --------------------------- launcher --------------------------------------
extern "C" void kernel_launch(void* const* d_in, const int* in_sizes, int n_in,
                              void* d_out, int out_size, void* d_ws, size_t ws_size,
                              hipStream_t stream) {
  const float* x   = (const float*)d_in[0];
  const float* ve  = (const float*)d_in[1];
  const float* qw  = (const float*)d_in[2];
  const float* lam = (const float*)d_in[3];
  const float* pw  = (const float*)d_in[4];
  float* out = (float*)d_out;

  unsigned short* ws = (unsigned short*)d_ws;
  unsigned short* x_bf  = ws;                                // 4096*1024
  unsigned short* wqkv  = x_bf + (size_t)4096 * 1024;        // 3072*1024
  unsigned short* wproj = wqkv + (size_t)3072 * 1024;        // 1024*1024
  unsigned short* qkv   = wproj + (size_t)1024 * 1024;       // 4096*3072
  unsigned short* Qb    = qkv + (size_t)4096 * 3072;         // 16*128*2048
  unsigned short* Kb    = Qb + (size_t)4096 * 1024;
  unsigned short* Vm    = Kb + (size_t)4096 * 1024;
  unsigned short* Vb    = Vm + (size_t)4096 * 1024;
  unsigned short* Yb    = Vb + (size_t)4096 * 1024;
  float* ct = (float*)(Yb + (size_t)4096 * 1024);            // 4096*32
  float* st = ct + 4096 * 32;

  rope_tab<<<512, 256, 0, stream>>>(ct, st);
  cast_f2b8<<<2048, 256, 0, stream>>>(x, x_bf, 524288);
  cast_f2b8<<<1536, 256, 0, stream>>>(qw, wqkv, 393216);
  cast_f2b8<<<512, 256, 0, stream>>>(pw, wproj, 131072);
  gemm_bt<1><<<768, 256, 0, stream>>>(x_bf, wqkv, (void*)qkv, 4096, 3072, 1024);
  fuse_qkv<<<256, 256, 0, stream>>>(qkv, ve, lam, ct, st, Qb, Kb, Vm);
  transpose_v<<<1024, 256, 0, stream>>>(Vm, Vb);
  attn_fa<<<2048, 256, 0, stream>>>(Qb, Kb, Vb, Yb);
  gemm_bt<0><<<256, 256, 0, stream>>>(Yb, wproj, (void*)out, 4096, 1024, 1024);
}

// Round 9
// 167.576 us; speedup vs baseline: 1.4783x; 1.0371x over previous
//
#include <hip/hip_runtime.h>
#include <stdint.h>

// ---------------------------------------------------------------------------
// CausalSelfAttention (T=4096, DIM=1024, 16 heads x 64) on gfx950, bf16 MFMA.
// Pipeline: cast->bf16 | rope tables | GEMM1 qkv | fuse(vmix,rms,rope ->
//           BLOCKED Q/K + BLOCKED V^T via LDS transpose) | flash attention
//           (swapped 32x32, split-KV x4, direct coalesced fragment loads,
//           ones-MFMA rowsum, shfl_xor exchanges) | GEMM2 -> fp32 out
//
// Blocked layout: per (head, 32-kv tile) 4KB block; fragment r of lane l at
// byte r*1024 + l*16. Fragment loads are plain coalesced global_load_dwordx4.
// ---------------------------------------------------------------------------

typedef __attribute__((ext_vector_type(8))) __bf16 bf16x8;
typedef __attribute__((ext_vector_type(8))) unsigned short u16x8;
typedef __attribute__((ext_vector_type(4))) float f32x4;
typedef __attribute__((ext_vector_type(16))) float f32x16;

union U8 { u16x8 s; bf16x8 b; };
union PF { unsigned int u[4]; u16x8 s; bf16x8 b; };

__device__ __forceinline__ float bf2f(unsigned short u) {
  union { unsigned int i; float f; } c; c.i = ((unsigned int)u) << 16; return c.f;
}
__device__ __forceinline__ unsigned short f2bf(float f) {
  union { __bf16 h; unsigned short u; } c; c.h = (__bf16)f; return c.u;
}
__device__ __forceinline__ unsigned int pk2(float lo, float hi) {
  return (unsigned int)f2bf(lo) | ((unsigned int)f2bf(hi) << 16);
}

// async global->LDS, 16B per lane (GEMM staging only)
#define GLOAD16(gp, lp)                                                         \
  __builtin_amdgcn_global_load_lds(                                             \
      (const __attribute__((address_space(1))) void*)(gp),                      \
      (__attribute__((address_space(3))) void*)(lp), 16, 0, 0)

#define MFMA16(a, b, c) __builtin_amdgcn_mfma_f32_16x16x32_bf16((a), (b), (c), 0, 0, 0)
#define MFMA32(a, b, c) __builtin_amdgcn_mfma_f32_32x32x16_bf16((a), (b), (c), 0, 0, 0)

constexpr float ATTN_SCALE = 0.12f;
constexpr float LOG2E = 1.44269504088896340736f;
constexpr float QSCALE = ATTN_SCALE * LOG2E;  // folded into Q at fuse stage

// --------------------------- rope tables -----------------------------------
__global__ void rope_tab(float* __restrict__ ct, float* __restrict__ st) {
  const int i = blockIdx.x * 256 + threadIdx.x;
  if (i >= 4096 * 32) return;
  const int tt = i >> 5, k = i & 31;
  float cv = 1.0f, sv = 0.0f;
  if (k < 16) {
    const float af = powf(1.0f / 1024.0f, (float)k * (1.0f / 15.0f));
    const float th = (float)tt * af;
    cv = cosf(th);
    sv = sinf(th);
  }
  ct[i] = cv; st[i] = sv;
}

// --------------------------- f32 -> bf16 cast ------------------------------
__global__ void cast_f2b8(const float* __restrict__ in, unsigned short* __restrict__ out, int n8) {
  const int i = blockIdx.x * 256 + threadIdx.x;
  if (i >= n8) return;
  const float4 a = ((const float4*)in)[2 * i];
  const float4 b = ((const float4*)in)[2 * i + 1];
  u16x8 o;
  o[0] = f2bf(a.x); o[1] = f2bf(a.y); o[2] = f2bf(a.z); o[3] = f2bf(a.w);
  o[4] = f2bf(b.x); o[5] = f2bf(b.y); o[6] = f2bf(b.z); o[7] = f2bf(b.w);
  ((u16x8*)out)[i] = o;
}

// --------------------------- GEMM: C[M][N] = A[M][K] * B[N][K]^T -----------
template <int OUT_BF16>
__global__ __launch_bounds__(256) void gemm_bt(
    const unsigned short* __restrict__ A, const unsigned short* __restrict__ B,
    void* __restrict__ Cout, int M, int N, int K) {
  __shared__ unsigned short lA[128 * 32];
  __shared__ unsigned short lB[128 * 32];
  const int nbn = N >> 7;
  const int bm = blockIdx.x / nbn, bn = blockIdx.x % nbn;
  const int t = threadIdx.x;
  const int w = t >> 6, l = t & 63;
  const int g = l >> 4, c = l & 15;
  const int wr = (w >> 1) * 64, wc = (w & 1) * 64;

  const int srow = t >> 2;
  const int scol = ((t & 3) << 4) ^ ((srow & 3) << 4);  // byte col, XOR swizzle
  const char* ga = (const char*)(A + (size_t)(bm * 128 + srow) * K) + scol;
  const char* gb = (const char*)(B + (size_t)(bn * 128 + srow) * K) + scol;
  const size_t rowK2 = (size_t)64 * K * 2;
  char* la_dst = (char*)lA + t * 16;
  char* lb_dst = (char*)lB + t * 16;

  f32x4 acc[4][4] = {};

  for (int kt = 0; kt < K; kt += 32) {
    const char* gak = ga + (size_t)kt * 2;
    const char* gbk = gb + (size_t)kt * 2;
    GLOAD16(gak, la_dst);
    GLOAD16(gak + rowK2, la_dst + 4096);
    GLOAD16(gbk, lb_dst);
    GLOAD16(gbk + rowK2, lb_dst + 4096);
    __syncthreads();
    U8 af[4], bfr[4];
#pragma unroll
    for (int mi = 0; mi < 4; ++mi) {
      const int row = wr + 16 * mi + c;
      af[mi].s = *(const u16x8*)((const char*)lA + row * 64 + ((16 * g) ^ ((row & 3) << 4)));
    }
#pragma unroll
    for (int ni = 0; ni < 4; ++ni) {
      const int row = wc + 16 * ni + c;
      bfr[ni].s = *(const u16x8*)((const char*)lB + row * 64 + ((16 * g) ^ ((row & 3) << 4)));
    }
#pragma unroll
    for (int mi = 0; mi < 4; ++mi)
#pragma unroll
      for (int ni = 0; ni < 4; ++ni)
        acc[mi][ni] = MFMA16(af[mi].b, bfr[ni].b, acc[mi][ni]);
    __syncthreads();
  }
#pragma unroll
  for (int mi = 0; mi < 4; ++mi) {
#pragma unroll
    for (int ni = 0; ni < 4; ++ni) {
#pragma unroll
      for (int r = 0; r < 4; ++r) {
        const int row = bm * 128 + wr + 16 * mi + 4 * g + r;
        const int col = bn * 128 + wc + 16 * ni + c;
        const float v = acc[mi][ni][r];
        if (OUT_BF16)
          ((unsigned short*)Cout)[(size_t)row * N + col] = f2bf(v);
        else
          ((float*)Cout)[(size_t)row * N + col] = v;
      }
    }
  }
}

// --------------------------- fuse: vmix + rmsnorm + rope -> blocked --------
__device__ __forceinline__ void load64f(const unsigned short* p, float* x) {
#pragma unroll
  for (int j = 0; j < 8; ++j) {
    const u16x8 v = *(const u16x8*)(p + 8 * j);
#pragma unroll
    for (int e = 0; e < 8; ++e) x[8 * j + e] = bf2f(v[e]);
  }
}

// store into blocked layout: chunk j (8 elems) at outp + 256*j
__device__ __forceinline__ void rmsrope_store_blk(const float* x, const float* ct,
                                                  const float* st, unsigned short* outp,
                                                  float pscale) {
  float ms = 0.f;
#pragma unroll
  for (int j = 0; j < 64; ++j) ms += x[j] * x[j];
  const float sc = rsqrtf(ms * (1.0f / 64.0f) + 1.1920928955078125e-7f) * pscale;
  float y[64];
#pragma unroll
  for (int j = 0; j < 32; ++j) {
    const float cc = ct[j], ss = st[j];
    const float a = x[j] * sc, b = x[j + 32] * sc;
    y[j] = a * cc + b * ss;
    y[j + 32] = b * cc - a * ss;
  }
#pragma unroll
  for (int j = 0; j < 8; ++j) {
    u16x8 o;
#pragma unroll
    for (int e = 0; e < 8; ++e) o[e] = f2bf(y[8 * j + e]);
    *(u16x8*)(outp + 256 * j) = o;
  }
}

// block = (head, 8 kv-tiles of 32 rows). Q/K written blocked directly; V
// mixed then transposed through a per-group LDS tile into blocked V^T.
__global__ __launch_bounds__(256) void fuse_qkv(
    const unsigned short* __restrict__ qkv,  // [4096][3072] bf16
    const float* __restrict__ ve,            // [4096][1024]
    const float* __restrict__ lam,           // [2]
    const float* __restrict__ ct, const float* __restrict__ st,  // [4096][32]
    unsigned short* __restrict__ Qb,  // blocked [16][128 tiles][2048]
    unsigned short* __restrict__ Kb,  // blocked
    unsigned short* __restrict__ Vb)  // blocked V^T
{
  __shared__ unsigned short vtile[8][32][65];  // [group][kv][d], +1 pad
  const int b = (int)blockIdx.x;  // 256 blocks
  const int h = b & 15, tg = b >> 4;
  const int t = threadIdx.x;
  const int g = t >> 5, lq = t & 31;
  const int ti = tg * 8 + g;       // 32-row tile 0..127
  const int tt = ti * 32 + lq;

  const unsigned short* base = qkv + (size_t)tt * 3072 + h * 64;
  const float* ctp = ct + tt * 32;
  const float* stp = st + tt * 32;
  const size_t blk = (size_t)h * 262144 + (size_t)ti * 2048 + lq * 8;

  float x[64];
  load64f(base, x);
  rmsrope_store_blk(x, ctp, stp, Qb + blk, QSCALE);
  load64f(base + 1024, x);
  rmsrope_store_blk(x, ctp, stp, Kb + blk, 1.0f);

  // v mix -> LDS transpose tile
  const float l0 = lam[0], l1 = lam[1];
  const float* vp = ve + (size_t)tt * 1024 + h * 64;
  load64f(base + 2048, x);
#pragma unroll
  for (int j = 0; j < 64; ++j) vtile[g][lq][j] = f2bf(l0 * x[j] + l1 * vp[j]);
  __syncthreads();

  // write blocked V^T: frag r, lane (hi,lq): elems j = V^T[lq+32*(r&1)]
  //   [kv = 16*(r>>1) + 8*hi + j]
  unsigned short* vo = Vb + (size_t)h * 262144 + (size_t)ti * 2048 + lq * 8;
#pragma unroll
  for (int r = 0; r < 4; ++r) {
    const int d = lq + 32 * (r & 1);
#pragma unroll
    for (int hi = 0; hi < 2; ++hi) {
      u16x8 o;
#pragma unroll
      for (int j = 0; j < 8; ++j) o[j] = vtile[g][16 * (r >> 1) + 8 * hi + j][d];
      *(u16x8*)(vo + r * 512 + hi * 256) = o;
    }
  }
}

// --------------------------- flash attention -------------------------------
// block = (head, 32 q-rows), 4 waves; split-KV: wave w owns kv-tiles
// ti = w, w+4, ... (KVBLK=32), private (m, osum, O^T), merged once via LDS.
// Direct coalesced fragment loads from blocked layouts; zero main-loop LDS.
// Row-sum on the MFMA pipe (ones-MFMA); cross-half exchange via shfl_xor(32)
// (proven; permlane retry deferred).
__global__ __launch_bounds__(256, 4) void attn_fa(
    const unsigned short* __restrict__ Qb,  // blocked (scaled)
    const unsigned short* __restrict__ Kb,  // blocked
    const unsigned short* __restrict__ Vb,  // blocked V^T
    unsigned short* __restrict__ Y)         // [4096][1024]
{
  __shared__ float oL[4][64][33];   // per-wave partial O^T
  __shared__ float mlL[4][2][32];   // per-wave m / ls per q row

  const int b = (int)blockIdx.x;
  const int h = 2 * (b & 7) + ((b >> 3) & 1);  // same-h -> same XCD (b%8)
  const int qb = 127 - (b >> 4);               // longest first
  const int q0 = qb * 32;
  const int t = threadIdx.x;
  const int w = t >> 6, l = t & 63;
  const int lq = l & 31;    // this lane's q row
  const int hi = l >> 5;    // k/kv half selector

  const unsigned short* kh = Kb + (size_t)h * 262144 + l * 8;
  const unsigned short* vh = Vb + (size_t)h * 262144 + l * 8;

  // Q fragments: blocked tile qb
  U8 qf[4];
  {
    const unsigned short* qp = Qb + (size_t)h * 262144 + qb * 2048 + l * 8;
#pragma unroll
    for (int dd = 0; dd < 4; ++dd) qf[dd].s = *(const u16x8*)(qp + dd * 512);
  }

  U8 onesf;
#pragma unroll
  for (int e = 0; e < 8; ++e) onesf.s[e] = 0x3F80;  // bf16 1.0

  f32x16 o0 = {}, o1 = {};   // O^T: d rows 0-31 / 32-63, col q = lq
  f32x16 osum = {};          // row-sum accum on MFMA pipe (read [0])
  float m = -3e38f;

  for (int ti = w; ti <= qb; ti += 4) {
    const unsigned short* kp = kh + ti * 2048;
    const unsigned short* vp = vh + ti * 2048;
    U8 kf[4], vf[4];
#pragma unroll
    for (int dd = 0; dd < 4; ++dd) kf[dd].s = *(const u16x8*)(kp + dd * 512);
#pragma unroll
    for (int r = 0; r < 4; ++r) vf[r].s = *(const u16x8*)(vp + r * 512);

    // ---- S^T = K * Q^T (32 kv x 32 q) ----
    __builtin_amdgcn_s_setprio(1);
    f32x16 s0 = {};
#pragma unroll
    for (int dd = 0; dd < 4; ++dd) s0 = MFMA32(kf[dd].b, qf[dd].b, s0);
    __builtin_amdgcn_s_setprio(0);

    // ---- causal mask (diagonal tile only): kv = kvr + 4*hi, q = lq ----
    if (ti == qb) {
      const int thr0 = lq - 4 * hi;
#pragma unroll
      for (int e = 0; e < 16; ++e) {
        const int kvr = (e & 3) + 8 * (e >> 2);
        if (kvr > thr0) s0[e] = -3e38f;
      }
    }

    // ---- online softmax (per q row = per lane) ----
    float pm;
    {
      float t0 = fmaxf(s0[0], s0[1]), t1 = fmaxf(s0[2], s0[3]);
      float t2 = fmaxf(s0[4], s0[5]), t3 = fmaxf(s0[6], s0[7]);
      float t4 = fmaxf(s0[8], s0[9]), t5 = fmaxf(s0[10], s0[11]);
      float t6 = fmaxf(s0[12], s0[13]), t7 = fmaxf(s0[14], s0[15]);
      pm = fmaxf(fmaxf(fmaxf(t0, t1), fmaxf(t2, t3)),
                 fmaxf(fmaxf(t4, t5), fmaxf(t6, t7)));
    }
    pm = fmaxf(pm, __shfl_xor(pm, 32));
    if (!__all(pm <= m + 8.0f)) {  // defer-max: rescale only on real growth
      const float mn = fmaxf(m, pm);
      const float alpha = exp2f(m - mn);
#pragma unroll
      for (int e = 0; e < 16; ++e) { o0[e] *= alpha; o1[e] *= alpha; }
      osum[0] *= alpha;
      m = mn;
    }
#pragma unroll
    for (int e = 0; e < 16; ++e) s0[e] = exp2f(s0[e] - m);

    // ---- P^T pack + cross-half redistribute (shfl) + PV + ones-rowsum ----
#define DO_SLAB(KS)                                                              \
  do {                                                                           \
    const unsigned int ua = pk2(s0[8 * (KS) + 0], s0[8 * (KS) + 1]);             \
    const unsigned int ub = pk2(s0[8 * (KS) + 2], s0[8 * (KS) + 3]);             \
    const unsigned int uc = pk2(s0[8 * (KS) + 4], s0[8 * (KS) + 5]);             \
    const unsigned int ud = pk2(s0[8 * (KS) + 6], s0[8 * (KS) + 7]);             \
    const unsigned int sa = (unsigned int)__shfl_xor((int)ua, 32);               \
    const unsigned int sb = (unsigned int)__shfl_xor((int)ub, 32);               \
    const unsigned int sc = (unsigned int)__shfl_xor((int)uc, 32);               \
    const unsigned int sd = (unsigned int)__shfl_xor((int)ud, 32);               \
    PF pf;                                                                       \
    pf.u[0] = hi ? sc : ua;                                                      \
    pf.u[1] = hi ? sd : ub;                                                      \
    pf.u[2] = hi ? uc : sa;                                                      \
    pf.u[3] = hi ? ud : sb;                                                      \
    __builtin_amdgcn_s_setprio(1);                                               \
    o0 = MFMA32(vf[2 * (KS)].b, pf.b, o0);                                       \
    o1 = MFMA32(vf[2 * (KS) + 1].b, pf.b, o1);                                   \
    osum = MFMA32(onesf.b, pf.b, osum);                                          \
    __builtin_amdgcn_s_setprio(0);                                               \
  } while (0)

    DO_SLAB(0);
    DO_SLAB(1);
#undef DO_SLAB
  }

  // ---- merge 4 per-wave partials via LDS ----
#pragma unroll
  for (int e = 0; e < 16; ++e) {
    const int d = (e & 3) + 8 * (e >> 2) + 4 * hi;
    oL[w][d][lq] = o0[e];
    oL[w][d + 32][lq] = o1[e];
  }
  if (hi == 0) { mlL[w][0][lq] = m; mlL[w][1][lq] = osum[0]; }
  __syncthreads();

  const int q = t >> 3, dblk = t & 7;
  const float m0 = mlL[0][0][q], m1 = mlL[1][0][q];
  const float m2 = mlL[2][0][q], m3 = mlL[3][0][q];
  const float mm = fmaxf(fmaxf(m0, m1), fmaxf(m2, m3));
  const float f0 = exp2f(m0 - mm), f1 = exp2f(m1 - mm);
  const float f2 = exp2f(m2 - mm), f3 = exp2f(m3 - mm);
  const float den = f0 * mlL[0][1][q] + f1 * mlL[1][1][q] +
                    f2 * mlL[2][1][q] + f3 * mlL[3][1][q];
  const float invd = 1.0f / den;
  u16x8 yv;
#pragma unroll
  for (int i = 0; i < 8; ++i) {
    const int d = dblk * 8 + i;
    const float a = f0 * oL[0][d][q] + f1 * oL[1][d][q] +
                    f2 * oL[2][d][q] + f3 * oL[3][d][q];
    yv[i] = f2bf(a * invd);
  }
  *(u16x8*)(Y + (size_t)(q0 + q) * 1024 + h * 64 + dblk * 8) = yv;
}

// --------------------------- launcher --------------------------------------
extern "C" void kernel_launch(void* const* d_in, const int* in_sizes, int n_in,
                              void* d_out, int out_size, void* d_ws, size_t ws_size,
                              hipStream_t stream) {
  const float* x   = (const float*)d_in[0];
  const float* ve  = (const float*)d_in[1];
  const float* qw  = (const float*)d_in[2];
  const float* lam = (const float*)d_in[3];
  const float* pw  = (const float*)d_in[4];
  float* out = (float*)d_out;

  unsigned short* ws = (unsigned short*)d_ws;
  unsigned short* x_bf  = ws;                                // 4096*1024
  unsigned short* wqkv  = x_bf + (size_t)4096 * 1024;        // 3072*1024
  unsigned short* wproj = wqkv + (size_t)3072 * 1024;        // 1024*1024
  unsigned short* qkv   = wproj + (size_t)1024 * 1024;       // 4096*3072
  unsigned short* Qb    = qkv + (size_t)4096 * 3072;         // 16*128*2048
  unsigned short* Kb    = Qb + (size_t)4096 * 1024;
  unsigned short* Vb    = Kb + (size_t)4096 * 1024;
  unsigned short* Yb    = Vb + (size_t)4096 * 1024;
  float* ct = (float*)(Yb + (size_t)4096 * 1024);            // 4096*32
  float* st = ct + 4096 * 32;

  rope_tab<<<512, 256, 0, stream>>>(ct, st);
  cast_f2b8<<<2048, 256, 0, stream>>>(x, x_bf, 524288);
  cast_f2b8<<<1536, 256, 0, stream>>>(qw, wqkv, 393216);
  cast_f2b8<<<512, 256, 0, stream>>>(pw, wproj, 131072);
  gemm_bt<1><<<768, 256, 0, stream>>>(x_bf, wqkv, (void*)qkv, 4096, 3072, 1024);
  fuse_qkv<<<256, 256, 0, stream>>>(qkv, ve, lam, ct, st, Qb, Kb, Vb);
  attn_fa<<<2048, 256, 0, stream>>>(Qb, Kb, Vb, Yb);
  gemm_bt<0><<<256, 256, 0, stream>>>(Yb, wproj, (void*)out, 4096, 1024, 1024);
}